// Round 1
// baseline (4374.652 us; speedup 1.0000x reference)
//
#include <hip/hip_runtime.h>

#define TM 64
#define TN 64
#define TK 16

// ---------------- fp32 tiled GEMM: Y = (relu?)(A) @ W (+bias) ----------------
// A: nrows x K (row-major), W: K x M (row-major), Y: nrows x M
template<bool RELU_A, bool ADD_BIAS>
__global__ __launch_bounds__(256)
void gemm_k(const float* __restrict__ A, const float* __restrict__ W,
            const float* __restrict__ bias, float* __restrict__ Y,
            int nrows, int K, int M)
{
    __shared__ float As[TK][TM + 4];   // padded: stride 68 floats (272B, 16B-aligned)
    __shared__ float Bs[TK][TN + 4];

    const int t   = threadIdx.x;
    const int row0 = blockIdx.x * TM;
    const int col0 = blockIdx.y * TN;
    const int tx = t & 15, ty = t >> 4;

    // load mapping
    const int ar = t >> 2;           // 0..63 (A tile row)
    const int ak = (t & 3) << 2;     // 0,4,8,12 (A tile k offset)
    const int br = t >> 4;           // 0..15 (B tile k row)
    const int bc = (t & 15) << 2;    // 0..60 (B tile col offset)

    float acc[4][4] = {};

    const int arow = row0 + ar;
    const float* Aptr = A + (size_t)arow * K + ak;
    const float* Wptr = W + (size_t)br * M + col0 + bc;

    for (int k0 = 0; k0 < K; k0 += TK) {
        float4 av = make_float4(0.f, 0.f, 0.f, 0.f);
        if (arow < nrows) {
            av = *reinterpret_cast<const float4*>(Aptr + k0);
            if (RELU_A) {
                av.x = fmaxf(av.x, 0.f); av.y = fmaxf(av.y, 0.f);
                av.z = fmaxf(av.z, 0.f); av.w = fmaxf(av.w, 0.f);
            }
        }
        float4 bv = *reinterpret_cast<const float4*>(Wptr + (size_t)k0 * M);

        __syncthreads();   // previous iteration's LDS reads must finish
        As[ak + 0][ar] = av.x;
        As[ak + 1][ar] = av.y;
        As[ak + 2][ar] = av.z;
        As[ak + 3][ar] = av.w;
        *reinterpret_cast<float4*>(&Bs[br][bc]) = bv;
        __syncthreads();

        #pragma unroll
        for (int kk = 0; kk < TK; ++kk) {
            const float4 a = *reinterpret_cast<const float4*>(&As[kk][ty << 2]);
            const float4 b = *reinterpret_cast<const float4*>(&Bs[kk][tx << 2]);
            const float am[4] = {a.x, a.y, a.z, a.w};
            const float bm[4] = {b.x, b.y, b.z, b.w};
            #pragma unroll
            for (int i = 0; i < 4; ++i)
                #pragma unroll
                for (int j = 0; j < 4; ++j)
                    acc[i][j] = fmaf(am[i], bm[j], acc[i][j]);
        }
    }

    #pragma unroll
    for (int i = 0; i < 4; ++i) {
        const int r = row0 + (ty << 2) + i;
        if (r < nrows) {
            float4 v = make_float4(acc[i][0], acc[i][1], acc[i][2], acc[i][3]);
            if (ADD_BIAS) {
                const float4 bb = *reinterpret_cast<const float4*>(bias + col0 + (tx << 2));
                v.x += bb.x; v.y += bb.y; v.z += bb.z; v.w += bb.w;
            }
            *reinterpret_cast<float4*>(Y + (size_t)r * M + col0 + (tx << 2)) = v;
        }
    }
}

// ---------------- edge scatter: y[sidx[e]] += scale*dinv[g]*dinv[s]*h[gidx[e]] ----------------
__global__ __launch_bounds__(256)
void scatter_k(const float* __restrict__ h, const int* __restrict__ gidx,
               const int* __restrict__ sidx, const float* __restrict__ dinv,
               float* __restrict__ y, int E, int F, int chunk_shift, float scale)
{
    const int tid = blockIdx.x * 256 + threadIdx.x;
    const int e = tid >> chunk_shift;
    if (e >= E) return;
    const int c = (tid & ((1 << chunk_shift) - 1)) << 2;
    const int g = gidx[e];
    const int s = sidx[e];
    const float w = scale * dinv[g] * dinv[s];
    const float4 hv = *reinterpret_cast<const float4*>(h + (size_t)g * F + c);
    float* yp = y + (size_t)s * F + c;
    atomicAdd(yp + 0, w * hv.x);
    atomicAdd(yp + 1, w * hv.y);
    atomicAdd(yp + 2, w * hv.z);
    atomicAdd(yp + 3, w * hv.w);
}

// ---------------- degree helpers ----------------
__global__ __launch_bounds__(256)
void zero_k(float* __restrict__ p, int n)
{
    const int i = blockIdx.x * 256 + threadIdx.x;
    if (i < n) p[i] = 0.f;
}

__global__ __launch_bounds__(256)
void deg_k(const int* __restrict__ src, const int* __restrict__ dst,
           float* __restrict__ deg_dst, float* __restrict__ deg_src, int E)
{
    const int e = blockIdx.x * 256 + threadIdx.x;
    if (e < E) {
        atomicAdd(deg_dst + dst[e], 1.f);
        atomicAdd(deg_src + src[e], 1.f);
    }
}

__global__ __launch_bounds__(256)
void dinv_k(float* __restrict__ p, int n)
{
    const int i = blockIdx.x * 256 + threadIdx.x;
    if (i < n) {
        const float v = p[i];
        p[i] = (v > 0.f) ? rsqrtf(v) : 0.f;
    }
}

extern "C" void kernel_launch(void* const* d_in, const int* in_sizes, int n_in,
                              void* d_out, int out_size, void* d_ws, size_t ws_size,
                              hipStream_t stream)
{
    const int N = 100000, E = 800000, F_IN = 128, C = 64, H = 128;

    const float* x       = (const float*)d_in[0];
    const int*   ei      = (const int*)d_in[1];
    const int*   src     = ei;          // edge_index[0]
    const int*   dst     = ei + E;      // edge_index[1]
    const float* W1_in   = (const float*)d_in[2];
    const float* W1_out  = (const float*)d_in[3];
    const float* W1_root = (const float*)d_in[4];
    const float* b1      = (const float*)d_in[5];
    const float* W2_in   = (const float*)d_in[6];
    const float* W2_out  = (const float*)d_in[7];
    const float* W2_root = (const float*)d_in[8];
    const float* b2      = (const float*)d_in[9];
    float* out = (float*)d_out;

    float* ws = (float*)d_ws;
    float* dinv_dst = ws;                         // N  (in-degree based)
    float* dinv_src = ws + N;                     // N  (out-degree based)
    float* hbuf     = ws + 2 * (size_t)N;         // N*H (reused)
    float* y1       = hbuf + (size_t)N * H;       // N*H

    const dim3 blk(256);

    // degrees -> dinv (both arrays contiguous)
    zero_k<<<(2 * N + 255) / 256, blk, 0, stream>>>(dinv_dst, 2 * N);
    deg_k<<<(E + 255) / 256, blk, 0, stream>>>(src, dst, dinv_dst, dinv_src, E);
    dinv_k<<<(2 * N + 255) / 256, blk, 0, stream>>>(dinv_dst, 2 * N);

    const dim3 g1((N + TM - 1) / TM, H / TN);   // 1563 x 2
    const dim3 g2((N + TM - 1) / TM, C / TN);   // 1563 x 1
    const int  sg1 = (int)(((size_t)E * (H / 4) + 255) / 256);  // 100000 blocks
    const int  sg2 = (int)(((size_t)E * (C / 4) + 255) / 256);  // 50000 blocks

    // ---- layer 1 ----
    // y1 = x @ W1_root + b1
    gemm_k<false, true ><<<g1, blk, 0, stream>>>(x, W1_root, b1, y1, N, F_IN, H);
    // in-direction: gather src, scatter dst, dinv from in-degrees
    gemm_k<false, false><<<g1, blk, 0, stream>>>(x, W1_in, nullptr, hbuf, N, F_IN, H);
    scatter_k<<<sg1, blk, 0, stream>>>(hbuf, src, dst, dinv_dst, y1, E, H, 5, 0.5f);
    // out-direction: gather dst, scatter src, dinv from out-degrees
    gemm_k<false, false><<<g1, blk, 0, stream>>>(x, W1_out, nullptr, hbuf, N, F_IN, H);
    scatter_k<<<sg1, blk, 0, stream>>>(hbuf, dst, src, dinv_src, y1, E, H, 5, 0.5f);

    // ---- layer 2 (ReLU folded into A loads) ----
    gemm_k<true, true ><<<g2, blk, 0, stream>>>(y1, W2_root, b2, out, N, H, C);
    gemm_k<true, false><<<g2, blk, 0, stream>>>(y1, W2_in, nullptr, hbuf, N, H, C);
    scatter_k<<<sg2, blk, 0, stream>>>(hbuf, src, dst, dinv_dst, out, E, C, 4, 0.5f);
    gemm_k<true, false><<<g2, blk, 0, stream>>>(y1, W2_out, nullptr, hbuf, N, H, C);
    scatter_k<<<sg2, blk, 0, stream>>>(hbuf, dst, src, dinv_src, out, E, C, 4, 0.5f);
}

// Round 2
// 659.389 us; speedup vs baseline: 6.6344x; 6.6344x over previous
//
#include <hip/hip_runtime.h>

#define TM 64
#define TN 64
#define TK 16

// ---------------- fp32 tiled GEMM: Y = (relu?)(A) @ W (+bias) ----------------
template<bool RELU_A, bool ADD_BIAS>
__global__ __launch_bounds__(256)
void gemm_k(const float* __restrict__ A, const float* __restrict__ W,
            const float* __restrict__ bias, float* __restrict__ Y,
            int nrows, int K, int M)
{
    __shared__ float As[TK][TM + 4];
    __shared__ float Bs[TK][TN + 4];

    const int t   = threadIdx.x;
    const int row0 = blockIdx.x * TM;
    const int col0 = blockIdx.y * TN;
    const int tx = t & 15, ty = t >> 4;

    const int ar = t >> 2;
    const int ak = (t & 3) << 2;
    const int br = t >> 4;
    const int bc = (t & 15) << 2;

    float acc[4][4] = {};

    const int arow = row0 + ar;
    const float* Aptr = A + (size_t)arow * K + ak;
    const float* Wptr = W + (size_t)br * M + col0 + bc;

    for (int k0 = 0; k0 < K; k0 += TK) {
        float4 av = make_float4(0.f, 0.f, 0.f, 0.f);
        if (arow < nrows) {
            av = *reinterpret_cast<const float4*>(Aptr + k0);
            if (RELU_A) {
                av.x = fmaxf(av.x, 0.f); av.y = fmaxf(av.y, 0.f);
                av.z = fmaxf(av.z, 0.f); av.w = fmaxf(av.w, 0.f);
            }
        }
        float4 bv = *reinterpret_cast<const float4*>(Wptr + (size_t)k0 * M);

        __syncthreads();
        As[ak + 0][ar] = av.x;
        As[ak + 1][ar] = av.y;
        As[ak + 2][ar] = av.z;
        As[ak + 3][ar] = av.w;
        *reinterpret_cast<float4*>(&Bs[br][bc]) = bv;
        __syncthreads();

        #pragma unroll
        for (int kk = 0; kk < TK; ++kk) {
            const float4 a = *reinterpret_cast<const float4*>(&As[kk][ty << 2]);
            const float4 b = *reinterpret_cast<const float4*>(&Bs[kk][tx << 2]);
            const float am[4] = {a.x, a.y, a.z, a.w};
            const float bm[4] = {b.x, b.y, b.z, b.w};
            #pragma unroll
            for (int i = 0; i < 4; ++i)
                #pragma unroll
                for (int j = 0; j < 4; ++j)
                    acc[i][j] = fmaf(am[i], bm[j], acc[i][j]);
        }
    }

    #pragma unroll
    for (int i = 0; i < 4; ++i) {
        const int r = row0 + (ty << 2) + i;
        if (r < nrows) {
            float4 v = make_float4(acc[i][0], acc[i][1], acc[i][2], acc[i][3]);
            if (ADD_BIAS) {
                const float4 bb = *reinterpret_cast<const float4*>(bias + col0 + (tx << 2));
                v.x += bb.x; v.y += bb.y; v.z += bb.z; v.w += bb.w;
            }
            *reinterpret_cast<float4*>(Y + (size_t)r * M + col0 + (tx << 2)) = v;
        }
    }
}

// ---------------- degree / dinv ----------------
__global__ __launch_bounds__(256)
void zero_i_k(int* __restrict__ p, int n)
{
    const int i = blockIdx.x * 256 + threadIdx.x;
    if (i < n) p[i] = 0;
}

__global__ __launch_bounds__(256)
void deg_k(const int* __restrict__ src, const int* __restrict__ dst,
           int* __restrict__ deg_in, int* __restrict__ deg_out, int E)
{
    const int e = blockIdx.x * 256 + threadIdx.x;
    if (e < E) {
        atomicAdd(deg_in + dst[e], 1);
        atomicAdd(deg_out + src[e], 1);
    }
}

__global__ __launch_bounds__(256)
void dinv_k(const int* __restrict__ deg, float* __restrict__ dinv, int n)
{
    const int i = blockIdx.x * 256 + threadIdx.x;
    if (i < n) {
        const int v = deg[i];
        dinv[i] = (v > 0) ? rsqrtf((float)v) : 0.f;
    }
}

// ---------------- prefix scan (3-phase) ----------------
__global__ __launch_bounds__(256)
void scan_block_k(const int* __restrict__ deg, int* __restrict__ rp,
                  int* __restrict__ bsum, int n)
{
    __shared__ int s[256];
    const int tid = threadIdx.x;
    const int i = blockIdx.x * 256 + tid;
    const int v = (i < n) ? deg[i] : 0;
    s[tid] = v;
    __syncthreads();
    #pragma unroll
    for (int off = 1; off < 256; off <<= 1) {
        int t = (tid >= off) ? s[tid - off] : 0;
        __syncthreads();
        s[tid] += t;
        __syncthreads();
    }
    if (i < n) rp[i] = s[tid] - v;           // exclusive within block
    if (tid == 255) bsum[blockIdx.x] = s[255];
}

__global__ __launch_bounds__(512)
void scan_top_k(int* __restrict__ bsum, int nb)
{
    __shared__ int s[512];
    const int tid = threadIdx.x;
    const int v = (tid < nb) ? bsum[tid] : 0;
    s[tid] = v;
    __syncthreads();
    #pragma unroll
    for (int off = 1; off < 512; off <<= 1) {
        int t = (tid >= off) ? s[tid - off] : 0;
        __syncthreads();
        s[tid] += t;
        __syncthreads();
    }
    if (tid < nb) bsum[tid] = s[tid] - v;    // exclusive block offsets
}

__global__ __launch_bounds__(256)
void scan_add_k(int* __restrict__ rp, int* __restrict__ cur,
                const int* __restrict__ bsum, int n, int total)
{
    const int i = blockIdx.x * 256 + threadIdx.x;
    if (i < n) {
        const int v = rp[i] + bsum[i >> 8];
        rp[i] = v;
        cur[i] = v;
    }
    if (i == 0) rp[n] = total;
}

// ---------------- CSR fill (edge -> sorted slot, weight precomputed) ----------------
__global__ __launch_bounds__(256)
void fill_k(const int* __restrict__ src, const int* __restrict__ dst,
            const float* __restrict__ dinv_in, const float* __restrict__ dinv_out,
            int* __restrict__ cur_in, int* __restrict__ cur_out,
            int* __restrict__ col_in, float* __restrict__ w_in,
            int* __restrict__ col_out, float* __restrict__ w_out, int E)
{
    const int e = blockIdx.x * 256 + threadIdx.x;
    if (e >= E) return;
    const int s = src[e], d = dst[e];
    const float wi = 0.5f * dinv_in[s] * dinv_in[d];    // alpha folded in
    const float wo = 0.5f * dinv_out[s] * dinv_out[d];
    const int p = atomicAdd(cur_in + d, 1);
    col_in[p] = s; w_in[p] = wi;
    const int q = atomicAdd(cur_out + s, 1);
    col_out[q] = d; w_out[q] = wo;
}

// ---------------- CSR gather: y[n][c] += sum_j w[j] * h[col[j]][c] ----------------
template<int F>
__global__ __launch_bounds__(256)
void gather_k(const float* __restrict__ h, const int* __restrict__ rp,
              const int* __restrict__ col, const float* __restrict__ w,
              float* __restrict__ y, int N)
{
    const int TPN = F / 4;
    const int tid = blockIdx.x * 256 + threadIdx.x;
    const int n = tid / TPN;
    if (n >= N) return;
    const int c = (tid % TPN) << 2;
    const int beg = rp[n], end = rp[n + 1];
    float* yp = y + (size_t)n * F + c;
    float4 acc = *reinterpret_cast<float4*>(yp);
    for (int j = beg; j < end; ++j) {
        const int g = col[j];
        const float ww = w[j];
        const float4 hv = *reinterpret_cast<const float4*>(h + (size_t)g * F + c);
        acc.x = fmaf(ww, hv.x, acc.x);
        acc.y = fmaf(ww, hv.y, acc.y);
        acc.z = fmaf(ww, hv.z, acc.z);
        acc.w = fmaf(ww, hv.w, acc.w);
    }
    *reinterpret_cast<float4*>(yp) = acc;
}

extern "C" void kernel_launch(void* const* d_in, const int* in_sizes, int n_in,
                              void* d_out, int out_size, void* d_ws, size_t ws_size,
                              hipStream_t stream)
{
    const int N = 100000, E = 800000, F_IN = 128, C = 64, H = 128;

    const float* x       = (const float*)d_in[0];
    const int*   ei      = (const int*)d_in[1];
    const int*   src     = ei;
    const int*   dst     = ei + E;
    const float* W1_in   = (const float*)d_in[2];
    const float* W1_out  = (const float*)d_in[3];
    const float* W1_root = (const float*)d_in[4];
    const float* b1      = (const float*)d_in[5];
    const float* W2_in   = (const float*)d_in[6];
    const float* W2_out  = (const float*)d_in[7];
    const float* W2_root = (const float*)d_in[8];
    const float* b2      = (const float*)d_in[9];
    float* out = (float*)d_out;

    // ---- workspace layout (4-byte elements; all offsets 16B-aligned) ----
    char* wsb = (char*)d_ws;
    int*   deg_in   = (int*)wsb;                       // N
    int*   deg_out  = deg_in + N;                      // N
    float* dinv_in  = (float*)(deg_out + N);           // N
    float* dinv_out = dinv_in + N;                     // N
    int*   rp_in    = (int*)(dinv_out + N);            // N+8
    int*   rp_out   = rp_in + N + 8;                   // N+8
    int*   cur_in   = rp_out + N + 8;                  // N
    int*   cur_out  = cur_in + N;                      // N
    int*   bsum_in  = cur_out + N;                     // 512
    int*   bsum_out = bsum_in + 512;                   // 512
    int*   col_in   = bsum_out + 512;                  // E
    int*   col_out  = col_in + E;                      // E
    float* w_in     = (float*)(col_out + E);           // E
    float* w_out    = w_in + E;                        // E
    float* hbuf     = w_out + E;                       // N*H
    float* y1       = hbuf + (size_t)N * H;            // N*H

    const dim3 blk(256);
    const int gN  = (N + 255) / 256;       // 391 blocks
    const int g2N = (2 * N + 255) / 256;
    const int gE  = (E + 255) / 256;

    // ---- degrees -> dinv ----
    zero_i_k<<<g2N, blk, 0, stream>>>(deg_in, 2 * N);
    deg_k<<<gE, blk, 0, stream>>>(src, dst, deg_in, deg_out, E);
    dinv_k<<<g2N, blk, 0, stream>>>(deg_in, dinv_in, 2 * N);

    // ---- CSR build (by dst: col=src) and CSC build (by src: col=dst) ----
    scan_block_k<<<gN, blk, 0, stream>>>(deg_in,  rp_in,  bsum_in,  N);
    scan_block_k<<<gN, blk, 0, stream>>>(deg_out, rp_out, bsum_out, N);
    scan_top_k<<<1, 512, 0, stream>>>(bsum_in,  gN);
    scan_top_k<<<1, 512, 0, stream>>>(bsum_out, gN);
    scan_add_k<<<gN, blk, 0, stream>>>(rp_in,  cur_in,  bsum_in,  N, E);
    scan_add_k<<<gN, blk, 0, stream>>>(rp_out, cur_out, bsum_out, N, E);
    fill_k<<<gE, blk, 0, stream>>>(src, dst, dinv_in, dinv_out,
                                   cur_in, cur_out, col_in, w_in, col_out, w_out, E);

    const dim3 gg1((N + TM - 1) / TM, H / TN);
    const dim3 gg2((N + TM - 1) / TM, C / TN);
    const int  ga1 = (N * (H / 4) + 255) / 256;   // gather grids
    const int  ga2 = (N * (C / 4) + 255) / 256;

    // ---- layer 1 ----
    gemm_k<false, true ><<<gg1, blk, 0, stream>>>(x, W1_root, b1, y1, N, F_IN, H);
    gemm_k<false, false><<<gg1, blk, 0, stream>>>(x, W1_in, nullptr, hbuf, N, F_IN, H);
    gather_k<128><<<ga1, blk, 0, stream>>>(hbuf, rp_in, col_in, w_in, y1, N);
    gemm_k<false, false><<<gg1, blk, 0, stream>>>(x, W1_out, nullptr, hbuf, N, F_IN, H);
    gather_k<128><<<ga1, blk, 0, stream>>>(hbuf, rp_out, col_out, w_out, y1, N);

    // ---- layer 2 (ReLU folded into A loads) ----
    gemm_k<true, true ><<<gg2, blk, 0, stream>>>(y1, W2_root, b2, out, N, H, C);
    gemm_k<true, false><<<gg2, blk, 0, stream>>>(y1, W2_in, nullptr, hbuf, N, H, C);
    gather_k<64><<<ga2, blk, 0, stream>>>(hbuf, rp_in, col_in, w_in, out, N);
    gemm_k<true, false><<<gg2, blk, 0, stream>>>(y1, W2_out, nullptr, hbuf, N, H, C);
    gather_k<64><<<ga2, blk, 0, stream>>>(hbuf, rp_out, col_out, w_out, out, N);
}

// Round 3
// 441.072 us; speedup vs baseline: 9.9182x; 1.4950x over previous
//
#include <hip/hip_runtime.h>

typedef __attribute__((ext_vector_type(8))) short bf16x8;
typedef __attribute__((ext_vector_type(4))) float f32x4;

__device__ __forceinline__ unsigned short f2bf(float f) {
    unsigned int u = __float_as_uint(f);
    u = (u + 0x7FFFu + ((u >> 16) & 1u)) >> 16;   // RTNE
    return (unsigned short)u;
}
__device__ __forceinline__ float bf2f(unsigned short v) {
    return __uint_as_float(((unsigned int)v) << 16);
}

// ================= bf16 MFMA GEMM: Y[nrows][BN] = A[nrows][128] @ W^T[BN][128]^T =================
// A: bf16 row-major (padded rows), BT: bf16 [BN][128] = W^T, K=128 fixed, BM=64.
// 4 waves in 2x2; each wave owns 32 rows x BN/2 cols.
template<int BN, bool OUT_BF16, bool ADD_BIAS>
__global__ __launch_bounds__(256)
void mfma_gemm_k(const unsigned short* __restrict__ A,
                 const unsigned short* __restrict__ BT,
                 const float* __restrict__ bias,
                 void* __restrict__ Yv, int nrows)
{
    constexpr int CF = BN / 32;            // 16-col frags per wave
    __shared__ unsigned short As[64 * 128];
    __shared__ unsigned short Bs[BN * 128];

    const int t  = threadIdx.x;
    const int w  = t >> 6, l = t & 63;
    const int g  = l >> 4, li = l & 15;
    const int wr = w >> 1, wc = w & 1;
    const int row0 = blockIdx.x * 64;

    // ---- stage A tile (contiguous 16KB; swizzle LDS dest: ck ^= row&7) ----
    {
        const int4* Ag = (const int4*)(A + (size_t)row0 * 128);
        #pragma unroll
        for (int i = 0; i < 4; ++i) {
            const int q   = t + 256 * i;        // 16B chunk id, 1024 total
            const int row = q >> 4;
            const int ck  = q & 15;
            const int4 v  = Ag[q];
            *(int4*)&As[row * 128 + ((ck ^ (row & 7)) << 3)] = v;
        }
    }
    // ---- stage B tile (W^T, contiguous BN*256B) ----
    {
        const int4* Bg = (const int4*)BT;
        #pragma unroll
        for (int i = 0; i < BN / 16; ++i) {
            const int q   = t + 256 * i;
            const int row = q >> 4;
            const int ck  = q & 15;
            const int4 v  = Bg[q];
            *(int4*)&Bs[row * 128 + ((ck ^ (row & 7)) << 3)] = v;
        }
    }
    __syncthreads();

    f32x4 acc[2][CF];
    #pragma unroll
    for (int rf = 0; rf < 2; ++rf)
        #pragma unroll
        for (int cf = 0; cf < CF; ++cf)
            acc[rf][cf] = (f32x4){0.f, 0.f, 0.f, 0.f};

    #pragma unroll
    for (int kk = 0; kk < 4; ++kk) {
        bf16x8 av[2], bv[CF];
        #pragma unroll
        for (int rf = 0; rf < 2; ++rf) {
            const int ar = wr * 32 + rf * 16 + li;
            const int ck = (kk * 4 + g) ^ (ar & 7);
            av[rf] = *(const bf16x8*)&As[ar * 128 + (ck << 3)];
        }
        #pragma unroll
        for (int cf = 0; cf < CF; ++cf) {
            const int bc = wc * (BN / 2) + cf * 16 + li;
            const int ck = (kk * 4 + g) ^ (bc & 7);
            bv[cf] = *(const bf16x8*)&Bs[bc * 128 + (ck << 3)];
        }
        #pragma unroll
        for (int rf = 0; rf < 2; ++rf)
            #pragma unroll
            for (int cf = 0; cf < CF; ++cf)
                acc[rf][cf] = __builtin_amdgcn_mfma_f32_16x16x32_bf16(
                    av[rf], bv[cf], acc[rf][cf], 0, 0, 0);
    }

    // ---- epilogue: D[row][col], row = 4*g + i (per frag), col = li ----
    #pragma unroll
    for (int rf = 0; rf < 2; ++rf) {
        #pragma unroll
        for (int i = 0; i < 4; ++i) {
            const int r = row0 + wr * 32 + rf * 16 + 4 * g + i;
            if (r < nrows) {
                #pragma unroll
                for (int cf = 0; cf < CF; ++cf) {
                    const int c = wc * (BN / 2) + cf * 16 + li;
                    float v = acc[rf][cf][i];
                    if (ADD_BIAS) v += bias[c];
                    if (OUT_BF16)
                        ((unsigned short*)Yv)[(size_t)r * BN + c] = f2bf(v);
                    else
                        ((float*)Yv)[(size_t)r * BN + c] = v;
                }
            }
        }
    }
}

// ================= conversions =================
// fp32 -> bf16, 8 elems/thread; pads [valid, total) with zeros; optional ReLU.
template<bool RELU>
__global__ __launch_bounds__(256)
void cvt_bf16_k(const float* __restrict__ in, unsigned short* __restrict__ out,
                int total8, int valid8)
{
    const int q = blockIdx.x * 256 + threadIdx.x;
    if (q >= total8) return;
    unsigned short o[8];
    if (q < valid8) {
        const float4 a = *(const float4*)(in + (size_t)q * 8);
        const float4 b = *(const float4*)(in + (size_t)q * 8 + 4);
        float v[8] = {a.x, a.y, a.z, a.w, b.x, b.y, b.z, b.w};
        #pragma unroll
        for (int j = 0; j < 8; ++j) {
            float f = RELU ? fmaxf(v[j], 0.f) : v[j];
            o[j] = f2bf(f);
        }
    } else {
        #pragma unroll
        for (int j = 0; j < 8; ++j) o[j] = 0;
    }
    *(int4*)(out + (size_t)q * 8) = *(int4*)o;
}

// W[K=128][M] fp32 -> WT[M][128] bf16  (M = 128 or 64)
__global__ __launch_bounds__(256)
void wtrans_k(const float* __restrict__ W, unsigned short* __restrict__ WT, int M)
{
    const int tid = blockIdx.x * 256 + threadIdx.x;
    if (tid >= 128 * M) return;
    const int m = tid & (M - 1);
    const int k = tid / M;
    WT[m * 128 + k] = f2bf(W[(size_t)k * M + m]);
}

// ================= degree / dinv =================
__global__ __launch_bounds__(256)
void zero_i_k(int* __restrict__ p, int n)
{
    const int i = blockIdx.x * 256 + threadIdx.x;
    if (i < n) p[i] = 0;
}

__global__ __launch_bounds__(256)
void deg_k(const int* __restrict__ src, const int* __restrict__ dst,
           int* __restrict__ deg_in, int* __restrict__ deg_out, int E)
{
    const int e = blockIdx.x * 256 + threadIdx.x;
    if (e < E) {
        atomicAdd(deg_in + dst[e], 1);
        atomicAdd(deg_out + src[e], 1);
    }
}

__global__ __launch_bounds__(256)
void dinv_k(const int* __restrict__ deg, float* __restrict__ dinv, int n)
{
    const int i = blockIdx.x * 256 + threadIdx.x;
    if (i < n) {
        const int v = deg[i];
        dinv[i] = (v > 0) ? rsqrtf((float)v) : 0.f;
    }
}

// ================= prefix scan (3-phase) =================
__global__ __launch_bounds__(256)
void scan_block_k(const int* __restrict__ deg, int* __restrict__ rp,
                  int* __restrict__ bsum, int n)
{
    __shared__ int s[256];
    const int tid = threadIdx.x;
    const int i = blockIdx.x * 256 + tid;
    const int v = (i < n) ? deg[i] : 0;
    s[tid] = v;
    __syncthreads();
    #pragma unroll
    for (int off = 1; off < 256; off <<= 1) {
        int tv = (tid >= off) ? s[tid - off] : 0;
        __syncthreads();
        s[tid] += tv;
        __syncthreads();
    }
    if (i < n) rp[i] = s[tid] - v;
    if (tid == 255) bsum[blockIdx.x] = s[255];
}

__global__ __launch_bounds__(512)
void scan_top_k(int* __restrict__ bsum, int nb)
{
    __shared__ int s[512];
    const int tid = threadIdx.x;
    const int v = (tid < nb) ? bsum[tid] : 0;
    s[tid] = v;
    __syncthreads();
    #pragma unroll
    for (int off = 1; off < 512; off <<= 1) {
        int tv = (tid >= off) ? s[tid - off] : 0;
        __syncthreads();
        s[tid] += tv;
        __syncthreads();
    }
    if (tid < nb) bsum[tid] = s[tid] - v;
}

__global__ __launch_bounds__(256)
void scan_add_k(int* __restrict__ rp, int* __restrict__ cur,
                const int* __restrict__ bsum, int n, int total)
{
    const int i = blockIdx.x * 256 + threadIdx.x;
    if (i < n) {
        const int v = rp[i] + bsum[i >> 8];
        rp[i] = v;
        cur[i] = v;
    }
    if (i == 0) rp[n] = total;
}

// ================= CSR fill: packed {col, weight} per edge =================
__global__ __launch_bounds__(256)
void fill2_k(const int* __restrict__ src, const int* __restrict__ dst,
             const float* __restrict__ dinv_in, const float* __restrict__ dinv_out,
             int* __restrict__ cur_in, int* __restrict__ cur_out,
             int2* __restrict__ cidw_in, int2* __restrict__ cidw_out, int E)
{
    const int e = blockIdx.x * 256 + threadIdx.x;
    if (e >= E) return;
    const int s = src[e], d = dst[e];
    const float wi = 0.5f * dinv_in[s] * dinv_in[d];   // alpha folded
    const float wo = 0.5f * dinv_out[s] * dinv_out[d];
    const int p = atomicAdd(cur_in + d, 1);
    cidw_in[p] = make_int2(s, __float_as_int(wi));
    const int q = atomicAdd(cur_out + s, 1);
    cidw_out[q] = make_int2(d, __float_as_int(wo));
}

// ================= fused 2-direction CSR gather (bf16 h, fp32 y RMW) =================
// y[n][:] += sum_in w*h_in[col][:] + sum_out w*h_out[col][:]
template<int F>
__global__ __launch_bounds__(256)
void gather2_k(const unsigned short* __restrict__ h_in,
               const unsigned short* __restrict__ h_out,
               const int* __restrict__ rp_in,  const int2* __restrict__ cidw_in,
               const int* __restrict__ rp_out, const int2* __restrict__ cidw_out,
               float* __restrict__ y, int N)
{
    constexpr int TPN = F / 8;                      // threads per node (8 bf16 cols each)
    const int tid = blockIdx.x * 256 + threadIdx.x;
    const int n = tid / TPN;
    if (n >= N) return;
    const int c8 = (tid % TPN) * 8;

    float acc[8];
    float* yp = y + (size_t)n * F + c8;
    {
        const float4 a = *(const float4*)yp;
        const float4 b = *(const float4*)(yp + 4);
        acc[0] = a.x; acc[1] = a.y; acc[2] = a.z; acc[3] = a.w;
        acc[4] = b.x; acc[5] = b.y; acc[6] = b.z; acc[7] = b.w;
    }

    #pragma unroll 1
    for (int pass = 0; pass < 2; ++pass) {
        const int*  rp   = pass ? rp_out   : rp_in;
        const int2* cidw = pass ? cidw_out : cidw_in;
        const unsigned short* h = pass ? h_out : h_in;
        const int beg = rp[n], end = rp[n + 1];
        for (int j = beg; j < end; ++j) {
            const int2 cw = cidw[j];
            const float ww = __int_as_float(cw.y);
            const unsigned short* hp = h + (size_t)cw.x * F + c8;
            const int4 hv4 = *(const int4*)hp;
            const unsigned short* hv = (const unsigned short*)&hv4;
            #pragma unroll
            for (int u = 0; u < 8; ++u)
                acc[u] = fmaf(ww, bf2f(hv[u]), acc[u]);
        }
    }

    float4 a = make_float4(acc[0], acc[1], acc[2], acc[3]);
    float4 b = make_float4(acc[4], acc[5], acc[6], acc[7]);
    *(float4*)yp = a;
    *(float4*)(yp + 4) = b;
}

// ================= launch =================
extern "C" void kernel_launch(void* const* d_in, const int* in_sizes, int n_in,
                              void* d_out, int out_size, void* d_ws, size_t ws_size,
                              hipStream_t stream)
{
    const int N = 100000, E = 800000, C = 64, H = 128;
    const int Npad = ((N + 63) / 64) * 64;          // 100032

    const float* x       = (const float*)d_in[0];
    const int*   ei      = (const int*)d_in[1];
    const int*   src     = ei;
    const int*   dst     = ei + E;
    const float* W1_in   = (const float*)d_in[2];
    const float* W1_out  = (const float*)d_in[3];
    const float* W1_root = (const float*)d_in[4];
    const float* b1      = (const float*)d_in[5];
    const float* W2_in   = (const float*)d_in[6];
    const float* W2_out  = (const float*)d_in[7];
    const float* W2_root = (const float*)d_in[8];
    const float* b2      = (const float*)d_in[9];
    float* out = (float*)d_out;

    // ---- workspace layout (all offsets 16B-aligned) ----
    char* p = (char*)d_ws;
    int*   deg_in   = (int*)p;            p += (size_t)N * 4;
    int*   deg_out  = (int*)p;            p += (size_t)N * 4;
    float* dinv_in  = (float*)p;          p += (size_t)N * 4;
    float* dinv_out = (float*)p;          p += (size_t)N * 4;
    int*   rp_in    = (int*)p;            p += (size_t)(N + 8) * 4;
    int*   rp_out   = (int*)p;            p += (size_t)(N + 8) * 4;
    int*   cur_in   = (int*)p;            p += (size_t)N * 4;
    int*   cur_out  = (int*)p;            p += (size_t)N * 4;
    int*   bsum_in  = (int*)p;            p += 512 * 4;
    int*   bsum_out = (int*)p;            p += 512 * 4;
    int2*  cidw_in  = (int2*)p;           p += (size_t)E * 8;
    int2*  cidw_out = (int2*)p;           p += (size_t)E * 8;
    unsigned short* wt1_in   = (unsigned short*)p;  p += 128 * 128 * 2;
    unsigned short* wt1_out  = (unsigned short*)p;  p += 128 * 128 * 2;
    unsigned short* wt1_root = (unsigned short*)p;  p += 128 * 128 * 2;
    unsigned short* wt2_in   = (unsigned short*)p;  p += 64 * 128 * 2;
    unsigned short* wt2_out  = (unsigned short*)p;  p += 64 * 128 * 2;
    unsigned short* wt2_root = (unsigned short*)p;  p += 64 * 128 * 2;
    unsigned short* xb   = (unsigned short*)p;      p += (size_t)Npad * 128 * 2; // reused as y1b
    unsigned short* h_in = (unsigned short*)p;      p += (size_t)N * 128 * 2;
    unsigned short* h_out= (unsigned short*)p;      p += (size_t)N * 128 * 2;
    float* y1 = (float*)p;                          p += (size_t)N * 128 * 4;

    const dim3 blk(256);
    const int gN  = (N + 255) / 256;
    const int g2N = (2 * N + 255) / 256;
    const int gE  = (E + 255) / 256;

    // ---- degrees -> dinv ----
    zero_i_k<<<g2N, blk, 0, stream>>>(deg_in, 2 * N);
    deg_k<<<gE, blk, 0, stream>>>(src, dst, deg_in, deg_out, E);
    dinv_k<<<g2N, blk, 0, stream>>>(deg_in, dinv_in, 2 * N);

    // ---- CSR build ----
    scan_block_k<<<gN, blk, 0, stream>>>(deg_in,  rp_in,  bsum_in,  N);
    scan_block_k<<<gN, blk, 0, stream>>>(deg_out, rp_out, bsum_out, N);
    scan_top_k<<<1, 512, 0, stream>>>(bsum_in,  gN);
    scan_top_k<<<1, 512, 0, stream>>>(bsum_out, gN);
    scan_add_k<<<gN, blk, 0, stream>>>(rp_in,  cur_in,  bsum_in,  N, E);
    scan_add_k<<<gN, blk, 0, stream>>>(rp_out, cur_out, bsum_out, N, E);
    fill2_k<<<gE, blk, 0, stream>>>(src, dst, dinv_in, dinv_out,
                                    cur_in, cur_out, cidw_in, cidw_out, E);

    // ---- weight transpose + x conversion ----
    wtrans_k<<<(128 * 128 + 255) / 256, blk, 0, stream>>>(W1_in,   wt1_in,   128);
    wtrans_k<<<(128 * 128 + 255) / 256, blk, 0, stream>>>(W1_out,  wt1_out,  128);
    wtrans_k<<<(128 * 128 + 255) / 256, blk, 0, stream>>>(W1_root, wt1_root, 128);
    wtrans_k<<<(128 * 64 + 255) / 256, blk, 0, stream>>>(W2_in,   wt2_in,   64);
    wtrans_k<<<(128 * 64 + 255) / 256, blk, 0, stream>>>(W2_out,  wt2_out,  64);
    wtrans_k<<<(128 * 64 + 255) / 256, blk, 0, stream>>>(W2_root, wt2_root, 64);

    const int tot8 = Npad * 128 / 8, val8 = N * 128 / 8;
    cvt_bf16_k<false><<<(tot8 + 255) / 256, blk, 0, stream>>>(x, xb, tot8, val8);

    const int gemm_blocks = Npad / 64;   // 1563
    const int ga1 = (N * (H / 8) + 255) / 256;
    const int ga2 = (N * (C / 8) + 255) / 256;

    // ---- layer 1 ----
    mfma_gemm_k<128, false, true ><<<gemm_blocks, blk, 0, stream>>>(xb, wt1_root, b1, y1, N);
    mfma_gemm_k<128, true,  false><<<gemm_blocks, blk, 0, stream>>>(xb, wt1_in,  nullptr, h_in,  N);
    mfma_gemm_k<128, true,  false><<<gemm_blocks, blk, 0, stream>>>(xb, wt1_out, nullptr, h_out, N);
    gather2_k<128><<<ga1, blk, 0, stream>>>(h_in, h_out, rp_in, cidw_in, rp_out, cidw_out, y1, N);

    // ---- ReLU + bf16 (y1 -> xb buffer reused) ----
    cvt_bf16_k<true><<<(tot8 + 255) / 256, blk, 0, stream>>>(y1, xb, tot8, val8);

    // ---- layer 2 ----
    mfma_gemm_k<64, false, true ><<<gemm_blocks, blk, 0, stream>>>(xb, wt2_root, b2, out, N);
    mfma_gemm_k<64, true,  false><<<gemm_blocks, blk, 0, stream>>>(xb, wt2_in,  nullptr, h_in,  N);
    mfma_gemm_k<64, true,  false><<<gemm_blocks, blk, 0, stream>>>(xb, wt2_out, nullptr, h_out, N);
    gather2_k<64><<<ga2, blk, 0, stream>>>(h_in, h_out, rp_in, cidw_in, rp_out, cidw_out, out, N);
}

// Round 4
// 302.489 us; speedup vs baseline: 14.4622x; 1.4581x over previous
//
#include <hip/hip_runtime.h>

typedef __attribute__((ext_vector_type(8))) short bf16x8;
typedef __attribute__((ext_vector_type(4))) float f32x4;

#define NB 196       // node buckets of 512
#define CAP 8192     // per-bucket edge capacity (avg 4096, sigma ~64)
#define SBLK 512     // bscatter blocks
#define ECH 1563     // edges per bscatter block (512*1563 >= 800000)

__device__ __forceinline__ unsigned short f2bf(float f) {
    unsigned int u = __float_as_uint(f);
    u = (u + 0x7FFFu + ((u >> 16) & 1u)) >> 16;   // RTNE
    return (unsigned short)u;
}
__device__ __forceinline__ float bf2f(unsigned short v) {
    return __uint_as_float(((unsigned int)v) << 16);
}

// ================= bf16 MFMA GEMM: Y[nrows][BN] = A[nrows][128] @ BT[BN][128]^T =================
template<int BN, bool OUT_BF16, bool ADD_BIAS>
__global__ __launch_bounds__(256)
void mfma_gemm_k(const unsigned short* __restrict__ A,
                 const unsigned short* __restrict__ BT,
                 const float* __restrict__ bias,
                 void* __restrict__ Yv, int nrows)
{
    constexpr int CF = BN / 32;
    __shared__ unsigned short As[64 * 128];
    __shared__ unsigned short Bs[BN * 128];

    const int t  = threadIdx.x;
    const int w  = t >> 6, l = t & 63;
    const int g  = l >> 4, li = l & 15;
    const int wr = w >> 1, wc = w & 1;
    const int row0 = blockIdx.x * 64;

    {
        const int4* Ag = (const int4*)(A + (size_t)row0 * 128);
        #pragma unroll
        for (int i = 0; i < 4; ++i) {
            const int q   = t + 256 * i;
            const int row = q >> 4;
            const int ck  = q & 15;
            const int4 v  = Ag[q];
            *(int4*)&As[row * 128 + ((ck ^ (row & 7)) << 3)] = v;
        }
    }
    {
        const int4* Bg = (const int4*)BT;
        #pragma unroll
        for (int i = 0; i < BN / 16; ++i) {
            const int q   = t + 256 * i;
            const int row = q >> 4;
            const int ck  = q & 15;
            const int4 v  = Bg[q];
            *(int4*)&Bs[row * 128 + ((ck ^ (row & 7)) << 3)] = v;
        }
    }
    __syncthreads();

    f32x4 acc[2][CF];
    #pragma unroll
    for (int rf = 0; rf < 2; ++rf)
        #pragma unroll
        for (int cf = 0; cf < CF; ++cf)
            acc[rf][cf] = (f32x4){0.f, 0.f, 0.f, 0.f};

    #pragma unroll
    for (int kk = 0; kk < 4; ++kk) {
        bf16x8 av[2], bv[CF];
        #pragma unroll
        for (int rf = 0; rf < 2; ++rf) {
            const int ar = wr * 32 + rf * 16 + li;
            const int ck = (kk * 4 + g) ^ (ar & 7);
            av[rf] = *(const bf16x8*)&As[ar * 128 + (ck << 3)];
        }
        #pragma unroll
        for (int cf = 0; cf < CF; ++cf) {
            const int bc = wc * (BN / 2) + cf * 16 + li;
            const int ck = (kk * 4 + g) ^ (bc & 7);
            bv[cf] = *(const bf16x8*)&Bs[bc * 128 + (ck << 3)];
        }
        #pragma unroll
        for (int rf = 0; rf < 2; ++rf)
            #pragma unroll
            for (int cf = 0; cf < CF; ++cf)
                acc[rf][cf] = __builtin_amdgcn_mfma_f32_16x16x32_bf16(
                    av[rf], bv[cf], acc[rf][cf], 0, 0, 0);
    }

    #pragma unroll
    for (int rf = 0; rf < 2; ++rf) {
        #pragma unroll
        for (int i = 0; i < 4; ++i) {
            const int r = row0 + wr * 32 + rf * 16 + 4 * g + i;
            if (r < nrows) {
                #pragma unroll
                for (int cf = 0; cf < CF; ++cf) {
                    const int c = wc * (BN / 2) + cf * 16 + li;
                    float v = acc[rf][cf][i];
                    if (ADD_BIAS) v += bias[c];
                    if (OUT_BF16)
                        ((unsigned short*)Yv)[(size_t)r * BN + c] = f2bf(v);
                    else
                        ((float*)Yv)[(size_t)r * BN + c] = v;
                }
            }
        }
    }
}

// ================= conversions =================
template<bool RELU>
__global__ __launch_bounds__(256)
void cvt_bf16_k(const float* __restrict__ in, unsigned short* __restrict__ out,
                int total8, int valid8)
{
    const int q = blockIdx.x * 256 + threadIdx.x;
    if (q >= total8) return;
    unsigned short o[8];
    if (q < valid8) {
        const float4 a = *(const float4*)(in + (size_t)q * 8);
        const float4 b = *(const float4*)(in + (size_t)q * 8 + 4);
        float v[8] = {a.x, a.y, a.z, a.w, b.x, b.y, b.z, b.w};
        #pragma unroll
        for (int j = 0; j < 8; ++j) {
            float f = RELU ? fmaxf(v[j], 0.f) : v[j];
            o[j] = f2bf(f);
        }
    } else {
        #pragma unroll
        for (int j = 0; j < 8; ++j) o[j] = 0;
    }
    *(int4*)(out + (size_t)q * 8) = *(int4*)o;
}

// all 6 weight transposes in one kernel: W[128][M] fp32 -> WT[M][128] bf16
__global__ __launch_bounds__(256)
void wtrans_all_k(const float* __restrict__ W1i, const float* __restrict__ W1o,
                  const float* __restrict__ W1r, const float* __restrict__ W2i,
                  const float* __restrict__ W2o, const float* __restrict__ W2r,
                  unsigned short* __restrict__ T1i, unsigned short* __restrict__ T1o,
                  unsigned short* __restrict__ T1r, unsigned short* __restrict__ T2i,
                  unsigned short* __restrict__ T2o, unsigned short* __restrict__ T2r)
{
    const int tid = blockIdx.x * 256 + threadIdx.x;   // 0..73727
    if (tid >= 3 * 16384 + 3 * 8192) return;
    const float* W; unsigned short* T; int M, r;
    if (tid < 49152) {
        const int w = tid / 16384; r = tid % 16384; M = 128;
        W = (w == 0) ? W1i : (w == 1) ? W1o : W1r;
        T = (w == 0) ? T1i : (w == 1) ? T1o : T1r;
    } else {
        const int u = tid - 49152;
        const int w = u / 8192; r = u % 8192; M = 64;
        W = (w == 0) ? W2i : (w == 1) ? W2o : W2r;
        T = (w == 0) ? T2i : (w == 1) ? T2o : T2r;
    }
    const int m = r & (M - 1);
    const int k = r / M;
    T[m * 128 + k] = f2bf(W[(size_t)k * M + m]);
}

// ================= bucketed CSR build =================
__global__ __launch_bounds__(256)
void zero_i_k(int* __restrict__ p, int n)
{
    const int i = blockIdx.x * 256 + threadIdx.x;
    if (i < n) p[i] = 0;
}

// scatter edges into per-bucket streams (block-level reservation)
__global__ __launch_bounds__(256)
void bscatter_k(const int* __restrict__ src, const int* __restrict__ dst,
                int* __restrict__ bcnt_in, int* __restrict__ bcnt_out,
                int* __restrict__ ebuf_in, int* __restrict__ ebuf_out, int E)
{
    __shared__ int lcnt_d[NB], lcnt_s[NB], lbase_d[NB], lbase_s[NB];
    const int t = threadIdx.x;
    const int c0 = blockIdx.x * ECH;
    const int c1 = min(E, c0 + ECH);
    for (int i = t; i < NB; i += 256) { lcnt_d[i] = 0; lcnt_s[i] = 0; }
    __syncthreads();
    int sv[7], dv[7], rd[7], rs[7];
    #pragma unroll
    for (int it = 0; it < 7; ++it) {
        const int e = c0 + it * 256 + t;
        if (e < c1) {
            const int s = src[e], d = dst[e];
            sv[it] = s; dv[it] = d;
            rd[it] = atomicAdd(&lcnt_d[d >> 9], 1);
            rs[it] = atomicAdd(&lcnt_s[s >> 9], 1);
        }
    }
    __syncthreads();
    for (int b = t; b < NB; b += 256) {
        lbase_d[b] = atomicAdd(&bcnt_in[b],  lcnt_d[b]);
        lbase_s[b] = atomicAdd(&bcnt_out[b], lcnt_s[b]);
    }
    __syncthreads();
    #pragma unroll
    for (int it = 0; it < 7; ++it) {
        const int e = c0 + it * 256 + t;
        if (e < c1) {
            const int s = sv[it], d = dv[it];
            const int bd = d >> 9, bs = s >> 9;
            ebuf_in [bd * CAP + lbase_d[bd] + rd[it]] = (s << 9) | (d & 511);
            ebuf_out[bs * CAP + lbase_s[bs] + rs[it]] = (d << 9) | (s & 511);
        }
    }
}

// exclusive scan over bucket counts (both directions), single block
__global__ __launch_bounds__(256)
void bscan_k(const int* __restrict__ bcnt_in, const int* __restrict__ bcnt_out,
             int* __restrict__ bsc_in, int* __restrict__ bsc_out)
{
    __shared__ int s[256];
    const int t = threadIdx.x;
    for (int pass = 0; pass < 2; ++pass) {
        const int* c = pass ? bcnt_out : bcnt_in;
        int* o = pass ? bsc_out : bsc_in;
        const int v = (t < NB) ? c[t] : 0;
        s[t] = v;
        __syncthreads();
        #pragma unroll
        for (int off = 1; off < 256; off <<= 1) {
            const int tv = (t >= off) ? s[t - off] : 0;
            __syncthreads();
            s[t] += tv;
            __syncthreads();
        }
        if (t < NB) o[t] = s[t] - v;
        if (t == NB - 1) o[NB] = s[t];
        __syncthreads();
    }
}

// per-bucket: degree histogram -> dinv + rp slices (coalesced writes)
__global__ __launch_bounds__(512)
void bdeg_k(const int* __restrict__ ebuf_in, const int* __restrict__ ebuf_out,
            const int* __restrict__ bcnt_in, const int* __restrict__ bcnt_out,
            const int* __restrict__ bsc_in, const int* __restrict__ bsc_out,
            float* __restrict__ dinv_in, float* __restrict__ dinv_out,
            int* __restrict__ rp_in, int* __restrict__ rp_out, int N, int E)
{
    __shared__ int cnt[512];
    const int t = threadIdx.x;
    const int dir = (blockIdx.x >= NB) ? 1 : 0;
    const int b = blockIdx.x - dir * NB;
    const int* ebuf = dir ? ebuf_out : ebuf_in;
    const int ne = (dir ? bcnt_out : bcnt_in)[b];
    const int e0 = b * CAP;
    cnt[t] = 0;
    __syncthreads();
    for (int j = t; j < ne; j += 512) atomicAdd(&cnt[ebuf[e0 + j] & 511], 1);
    __syncthreads();
    const int node = b * 512 + t;
    const int deg = cnt[t];
    float* dinv = dir ? dinv_out : dinv_in;
    if (node < N) dinv[node] = (deg > 0) ? rsqrtf((float)deg) : 0.f;
    #pragma unroll
    for (int off = 1; off < 512; off <<= 1) {
        const int tv = (t >= off) ? cnt[t - off] : 0;
        __syncthreads();
        cnt[t] += tv;
        __syncthreads();
    }
    int* rp = dir ? rp_out : rp_in;
    const int base = (dir ? bsc_out : bsc_in)[b];
    if (node < N) rp[node] = base + cnt[t] - deg;
    if (b == 0 && t == 0) rp[N] = E;
}

// per-bucket final CSR fill: LDS cur counters, windowed L2-resident writes
__global__ __launch_bounds__(512)
void bfill_k(const int* __restrict__ ebuf_in, const int* __restrict__ ebuf_out,
             const int* __restrict__ bcnt_in, const int* __restrict__ bcnt_out,
             const float* __restrict__ dinv_in, const float* __restrict__ dinv_out,
             const int* __restrict__ rp_in, const int* __restrict__ rp_out,
             int2* __restrict__ cidw_in, int2* __restrict__ cidw_out, int N)
{
    __shared__ int cur[512];
    __shared__ float dl[512];
    const int t = threadIdx.x;
    const int dir = (blockIdx.x >= NB) ? 1 : 0;
    const int b = blockIdx.x - dir * NB;
    const int* ebuf = dir ? ebuf_out : ebuf_in;
    const float* dinv = dir ? dinv_out : dinv_in;
    const int* rp = dir ? rp_out : rp_in;
    int2* cidw = dir ? cidw_out : cidw_in;
    const int ne = (dir ? bcnt_out : bcnt_in)[b];
    const int e0 = b * CAP;
    const int node = b * 512 + t;
    cur[t] = (node < N) ? rp[node] : 0;
    dl[t]  = (node < N) ? dinv[node] : 0.f;
    __syncthreads();
    for (int j = t; j < ne; j += 512) {
        const int p = ebuf[e0 + j];
        const int l = p & 511;
        const int o = p >> 9;
        const int slot = atomicAdd(&cur[l], 1);
        const float w = 0.5f * dl[l] * dinv[o];
        cidw[slot] = make_int2(o, __float_as_int(w));
    }
}

// ================= fused 2-direction CSR gather =================
// RELU_BF16: yout(bf16) = relu(ybase + msgs);  else: yout(fp32, ==ybase) += msgs
template<int F, bool RELU_BF16>
__global__ __launch_bounds__(256)
void gather2_k(const unsigned short* __restrict__ h_in,
               const unsigned short* __restrict__ h_out,
               const int* __restrict__ rp_in,  const int2* __restrict__ cidw_in,
               const int* __restrict__ rp_out, const int2* __restrict__ cidw_out,
               const float* __restrict__ ybase, void* __restrict__ yout, int N)
{
    constexpr int TPN = F / 8;
    const int tid = blockIdx.x * 256 + threadIdx.x;
    const int n = tid / TPN;
    if (n >= N) return;
    const int c8 = (tid % TPN) * 8;

    float acc[8];
    {
        const float* yp = ybase + (size_t)n * F + c8;
        const float4 a = *(const float4*)yp;
        const float4 b = *(const float4*)(yp + 4);
        acc[0] = a.x; acc[1] = a.y; acc[2] = a.z; acc[3] = a.w;
        acc[4] = b.x; acc[5] = b.y; acc[6] = b.z; acc[7] = b.w;
    }

    #pragma unroll 1
    for (int pass = 0; pass < 2; ++pass) {
        const int*  rp   = pass ? rp_out   : rp_in;
        const int2* cidw = pass ? cidw_out : cidw_in;
        const unsigned short* h = pass ? h_out : h_in;
        const int beg = rp[n], end = rp[n + 1];
        for (int j = beg; j < end; ++j) {
            const int2 cw = cidw[j];
            const float ww = __int_as_float(cw.y);
            const unsigned short* hp = h + (size_t)cw.x * F + c8;
            const int4 hv4 = *(const int4*)hp;
            const unsigned short* hv = (const unsigned short*)&hv4;
            #pragma unroll
            for (int u = 0; u < 8; ++u)
                acc[u] = fmaf(ww, bf2f(hv[u]), acc[u]);
        }
    }

    if (RELU_BF16) {
        unsigned short o[8];
        #pragma unroll
        for (int u = 0; u < 8; ++u) o[u] = f2bf(fmaxf(acc[u], 0.f));
        *(int4*)((unsigned short*)yout + (size_t)n * F + c8) = *(int4*)o;
    } else {
        float* yp = (float*)yout + (size_t)n * F + c8;
        *(float4*)yp       = make_float4(acc[0], acc[1], acc[2], acc[3]);
        *(float4*)(yp + 4) = make_float4(acc[4], acc[5], acc[6], acc[7]);
    }
}

// ================= launch =================
extern "C" void kernel_launch(void* const* d_in, const int* in_sizes, int n_in,
                              void* d_out, int out_size, void* d_ws, size_t ws_size,
                              hipStream_t stream)
{
    const int N = 100000, E = 800000, C = 64, H = 128;
    const int Npad = ((N + 63) / 64) * 64;          // 100032

    const float* x       = (const float*)d_in[0];
    const int*   ei      = (const int*)d_in[1];
    const int*   src     = ei;
    const int*   dst     = ei + E;
    const float* W1_in   = (const float*)d_in[2];
    const float* W1_out  = (const float*)d_in[3];
    const float* W1_root = (const float*)d_in[4];
    const float* b1      = (const float*)d_in[5];
    const float* W2_in   = (const float*)d_in[6];
    const float* W2_out  = (const float*)d_in[7];
    const float* W2_root = (const float*)d_in[8];
    const float* b2      = (const float*)d_in[9];
    float* out = (float*)d_out;

    // ---- workspace layout (16B-aligned offsets) ----
    char* p = (char*)d_ws;
    int*   bcnt_in  = (int*)p;            p += (size_t)(2 * NB + 8) * 4;
    int*   bcnt_out = bcnt_in + NB;
    int*   bsc_in   = (int*)p;            p += (size_t)(2 * (NB + 1) + 8) * 4;
    int*   bsc_out  = bsc_in + NB + 1;
    float* dinv_in  = (float*)p;          p += (size_t)N * 4;
    float* dinv_out = (float*)p;          p += (size_t)N * 4;
    int*   rp_in    = (int*)p;            p += (size_t)(N + 8) * 4;
    int*   rp_out   = (int*)p;            p += (size_t)(N + 8) * 4;
    int2*  cidw_in  = (int2*)p;           p += (size_t)E * 8;
    int2*  cidw_out = (int2*)p;           p += (size_t)E * 8;
    unsigned short* wt1_in   = (unsigned short*)p;  p += 128 * 128 * 2;
    unsigned short* wt1_out  = (unsigned short*)p;  p += 128 * 128 * 2;
    unsigned short* wt1_root = (unsigned short*)p;  p += 128 * 128 * 2;
    unsigned short* wt2_in   = (unsigned short*)p;  p += 64 * 128 * 2;
    unsigned short* wt2_out  = (unsigned short*)p;  p += 64 * 128 * 2;
    unsigned short* wt2_root = (unsigned short*)p;  p += 64 * 128 * 2;
    unsigned short* xb   = (unsigned short*)p;      p += (size_t)Npad * 128 * 2;
    unsigned short* h_in = (unsigned short*)p;      p += (size_t)N * 128 * 2;
    unsigned short* h_out= (unsigned short*)p;      p += (size_t)N * 128 * 2;
    float* y1 = (float*)p;                          p += (size_t)N * 128 * 4;
    // ebuf streams alias y1 (dead before first GEMM writes y1)
    int* ebuf_in  = (int*)y1;                       // NB*CAP ints = 6.4MB
    int* ebuf_out = ebuf_in + (size_t)NB * CAP;     // 6.4MB

    const dim3 blk(256);

    // ---- bucketed CSR build ----
    zero_i_k<<<(2 * NB + 255) / 256, blk, 0, stream>>>(bcnt_in, 2 * NB);
    bscatter_k<<<SBLK, blk, 0, stream>>>(src, dst, bcnt_in, bcnt_out,
                                         ebuf_in, ebuf_out, E);
    bscan_k<<<1, blk, 0, stream>>>(bcnt_in, bcnt_out, bsc_in, bsc_out);
    bdeg_k<<<2 * NB, 512, 0, stream>>>(ebuf_in, ebuf_out, bcnt_in, bcnt_out,
                                       bsc_in, bsc_out, dinv_in, dinv_out,
                                       rp_in, rp_out, N, E);
    bfill_k<<<2 * NB, 512, 0, stream>>>(ebuf_in, ebuf_out, bcnt_in, bcnt_out,
                                        dinv_in, dinv_out, rp_in, rp_out,
                                        cidw_in, cidw_out, N);

    // ---- weight transpose + x conversion ----
    wtrans_all_k<<<288, blk, 0, stream>>>(W1_in, W1_out, W1_root, W2_in, W2_out, W2_root,
                                          wt1_in, wt1_out, wt1_root, wt2_in, wt2_out, wt2_root);
    const int tot8 = Npad * 128 / 8, val8 = N * 128 / 8;
    cvt_bf16_k<false><<<(tot8 + 255) / 256, blk, 0, stream>>>(x, xb, tot8, val8);

    const int gemm_blocks = Npad / 64;   // 1563
    const int ga1 = (N * (H / 8) + 255) / 256;
    const int ga2 = (N * (C / 8) + 255) / 256;

    // ---- layer 1 ----
    mfma_gemm_k<128, false, true ><<<gemm_blocks, blk, 0, stream>>>(xb, wt1_root, b1, y1, N);
    mfma_gemm_k<128, true,  false><<<gemm_blocks, blk, 0, stream>>>(xb, wt1_in,  nullptr, h_in,  N);
    mfma_gemm_k<128, true,  false><<<gemm_blocks, blk, 0, stream>>>(xb, wt1_out, nullptr, h_out, N);
    // fused: xb = bf16(relu(y1 + msgs))
    gather2_k<128, true><<<ga1, blk, 0, stream>>>(h_in, h_out, rp_in, cidw_in,
                                                  rp_out, cidw_out, y1, xb, N);

    // ---- layer 2 ----
    mfma_gemm_k<64, false, true ><<<gemm_blocks, blk, 0, stream>>>(xb, wt2_root, b2, out, N);
    mfma_gemm_k<64, true,  false><<<gemm_blocks, blk, 0, stream>>>(xb, wt2_in,  nullptr, h_in,  N);
    mfma_gemm_k<64, true,  false><<<gemm_blocks, blk, 0, stream>>>(xb, wt2_out, nullptr, h_out, N);
    gather2_k<64, false><<<ga2, blk, 0, stream>>>(h_in, h_out, rp_in, cidw_in,
                                                  rp_out, cidw_out, out, out, N);
}

// Round 5
// 273.142 us; speedup vs baseline: 16.0161x; 1.1074x over previous
//
#include <hip/hip_runtime.h>

typedef __attribute__((ext_vector_type(8))) short bf16x8;
typedef __attribute__((ext_vector_type(4))) float f32x4;

#define NB 196       // node buckets of 512
#define CAP 8192     // per-bucket edge capacity (avg 4096, sigma ~64)
#define SBLK 256     // bscatter blocks
#define ECH 3125     // edges per bscatter block

__device__ __forceinline__ unsigned short f2bf(float f) {
    unsigned int u = __float_as_uint(f);
    u = (u + 0x7FFFu + ((u >> 16) & 1u)) >> 16;   // RTNE
    return (unsigned short)u;
}
__device__ __forceinline__ float bf2f(unsigned short v) {
    return __uint_as_float(((unsigned int)v) << 16);
}

// ================= 3-weight MFMA GEMM =================
// A[nrows][128] (fp32 source or bf16 buffer) @ BTcat[w][BNW][128]^T, w=0,1,2
// w=0: +bias -> Y0 bf16;  w=1: *0.5*dinv_in[row] -> Y1;  w=2: *0.5*dinv_out[row] -> Y2
template<int BNW, bool A_FP32>
__global__ __launch_bounds__(256)
void gemm3_k(const void* __restrict__ Av,
             const unsigned short* __restrict__ BTcat,
             const float* __restrict__ bias,
             const float* __restrict__ dinv_in, const float* __restrict__ dinv_out,
             unsigned short* __restrict__ Y0, unsigned short* __restrict__ Y1,
             unsigned short* __restrict__ Y2, int nrows)
{
    constexpr int CF = BNW / 32;            // col frags per wave
    __shared__ unsigned short As[64 * 128];
    __shared__ unsigned short Bs[BNW * 128];

    const int t  = threadIdx.x;
    const int w  = t >> 6, l = t & 63;
    const int g  = l >> 4, li = l & 15;
    const int wr = w >> 1, wc = w & 1;
    const int row0 = blockIdx.x * 64;

    // ---- stage A tile (swizzle: ck ^= row&7) ----
    if (A_FP32) {
        const float* Ag = (const float*)Av;
        #pragma unroll
        for (int i = 0; i < 4; ++i) {
            const int q   = t + 256 * i;
            const int row = q >> 4;
            const int ck  = q & 15;
            unsigned short o[8];
            if (row0 + row < nrows) {
                const float* src = Ag + (size_t)(row0 + row) * 128 + ck * 8;
                const float4 a = *(const float4*)src;
                const float4 b = *(const float4*)(src + 4);
                o[0]=f2bf(a.x); o[1]=f2bf(a.y); o[2]=f2bf(a.z); o[3]=f2bf(a.w);
                o[4]=f2bf(b.x); o[5]=f2bf(b.y); o[6]=f2bf(b.z); o[7]=f2bf(b.w);
            } else {
                #pragma unroll
                for (int u = 0; u < 8; ++u) o[u] = 0;
            }
            *(int4*)&As[row * 128 + ((ck ^ (row & 7)) << 3)] = *(int4*)o;
        }
    } else {
        const int4* Ag = (const int4*)((const unsigned short*)Av + (size_t)row0 * 128);
        #pragma unroll
        for (int i = 0; i < 4; ++i) {
            const int q   = t + 256 * i;
            const int row = q >> 4;
            const int ck  = q & 15;
            const int4 v  = Ag[q];
            *(int4*)&As[row * 128 + ((ck ^ (row & 7)) << 3)] = v;
        }
    }

    #pragma unroll 1
    for (int wgt = 0; wgt < 3; ++wgt) {
        __syncthreads();   // As ready / previous compute done
        // ---- stage Bs for this weight ----
        {
            const int4* Bg = (const int4*)(BTcat + (size_t)wgt * BNW * 128);
            #pragma unroll
            for (int i = 0; i < BNW / 16; ++i) {
                const int q   = t + 256 * i;
                const int row = q >> 4;
                const int ck  = q & 15;
                const int4 v  = Bg[q];
                *(int4*)&Bs[row * 128 + ((ck ^ (row & 7)) << 3)] = v;
            }
        }
        __syncthreads();

        f32x4 acc[2][CF];
        #pragma unroll
        for (int rf = 0; rf < 2; ++rf)
            #pragma unroll
            for (int cf = 0; cf < CF; ++cf)
                acc[rf][cf] = (f32x4){0.f, 0.f, 0.f, 0.f};

        #pragma unroll
        for (int kk = 0; kk < 4; ++kk) {
            bf16x8 av[2], bv[CF];
            #pragma unroll
            for (int rf = 0; rf < 2; ++rf) {
                const int ar = wr * 32 + rf * 16 + li;
                const int ck = (kk * 4 + g) ^ (ar & 7);
                av[rf] = *(const bf16x8*)&As[ar * 128 + (ck << 3)];
            }
            #pragma unroll
            for (int cf = 0; cf < CF; ++cf) {
                const int bc = wc * (BNW / 2) + cf * 16 + li;
                const int ck = (kk * 4 + g) ^ (bc & 7);
                bv[cf] = *(const bf16x8*)&Bs[bc * 128 + (ck << 3)];
            }
            #pragma unroll
            for (int rf = 0; rf < 2; ++rf)
                #pragma unroll
                for (int cf = 0; cf < CF; ++cf)
                    acc[rf][cf] = __builtin_amdgcn_mfma_f32_16x16x32_bf16(
                        av[rf], bv[cf], acc[rf][cf], 0, 0, 0);
        }

        unsigned short* Y = (wgt == 0) ? Y0 : (wgt == 1) ? Y1 : Y2;
        const float* dv = (wgt == 1) ? dinv_in : dinv_out;
        #pragma unroll
        for (int rf = 0; rf < 2; ++rf) {
            #pragma unroll
            for (int i = 0; i < 4; ++i) {
                const int r = row0 + wr * 32 + rf * 16 + 4 * g + i;
                if (r < nrows) {
                    const float s = (wgt == 0) ? 1.f : 0.5f * dv[r];
                    #pragma unroll
                    for (int cf = 0; cf < CF; ++cf) {
                        const int c = wc * (BNW / 2) + cf * 16 + li;
                        float v = acc[rf][cf][i];
                        v = (wgt == 0) ? (v + bias[c]) : (v * s);
                        Y[(size_t)r * BNW + c] = f2bf(v);
                    }
                }
            }
        }
    }
}

// ================= weight transpose: cat layout [root|in|out] =================
__global__ __launch_bounds__(256)
void wtrans_all_k(const float* __restrict__ W1r, const float* __restrict__ W1i,
                  const float* __restrict__ W1o, const float* __restrict__ W2r,
                  const float* __restrict__ W2i, const float* __restrict__ W2o,
                  unsigned short* __restrict__ T1, unsigned short* __restrict__ T2)
{
    const int tid = blockIdx.x * 256 + threadIdx.x;   // 0..73727
    if (tid >= 3 * 16384 + 3 * 8192) return;
    const float* W; unsigned short* T; int M, r, base;
    if (tid < 49152) {
        const int w = tid / 16384; r = tid % 16384; M = 128;
        W = (w == 0) ? W1r : (w == 1) ? W1i : W1o;
        T = T1; base = w * 128;
    } else {
        const int u = tid - 49152;
        const int w = u / 8192; r = u % 8192; M = 64;
        W = (w == 0) ? W2r : (w == 1) ? W2i : W2o;
        T = T2; base = w * 64;
    }
    const int m = r & (M - 1);
    const int k = r / M;
    T[(size_t)(base + m) * 128 + k] = f2bf(W[(size_t)k * M + m]);
}

// ================= bucketed CSR build =================
__global__ __launch_bounds__(256)
void zero_i_k(int* __restrict__ p, int n)
{
    const int i = blockIdx.x * 256 + threadIdx.x;
    if (i < n) p[i] = 0;
}

// scatter edges into per-bucket streams (two-pass, LDS counters)
__global__ __launch_bounds__(256)
void bscatter_k(const int* __restrict__ src, const int* __restrict__ dst,
                int* __restrict__ bcnt_in, int* __restrict__ bcnt_out,
                int* __restrict__ ebuf_in, int* __restrict__ ebuf_out, int E)
{
    __shared__ int lcnt_d[NB], lcnt_s[NB], lbase_d[NB], lbase_s[NB];
    const int t = threadIdx.x;
    const int c0 = blockIdx.x * ECH;
    const int c1 = min(E, c0 + ECH);
    for (int i = t; i < NB; i += 256) { lcnt_d[i] = 0; lcnt_s[i] = 0; }
    __syncthreads();
    for (int e = c0 + t; e < c1; e += 256) {
        atomicAdd(&lcnt_d[dst[e] >> 9], 1);
        atomicAdd(&lcnt_s[src[e] >> 9], 1);
    }
    __syncthreads();
    for (int b = t; b < NB; b += 256) {
        lbase_d[b] = atomicAdd(&bcnt_in[b],  lcnt_d[b]);
        lbase_s[b] = atomicAdd(&bcnt_out[b], lcnt_s[b]);
        lcnt_d[b] = 0; lcnt_s[b] = 0;
    }
    __syncthreads();
    for (int e = c0 + t; e < c1; e += 256) {
        const int s = src[e], d = dst[e];
        const int bd = d >> 9, bs = s >> 9;
        const int rd = atomicAdd(&lcnt_d[bd], 1);
        ebuf_in [bd * CAP + lbase_d[bd] + rd] = (s << 9) | (d & 511);
        const int rs = atomicAdd(&lcnt_s[bs], 1);
        ebuf_out[bs * CAP + lbase_s[bs] + rs] = (d << 9) | (s & 511);
    }
}

// exclusive scan over bucket counts (both directions), single block
__global__ __launch_bounds__(256)
void bscan_k(const int* __restrict__ bcnt_in, const int* __restrict__ bcnt_out,
             int* __restrict__ bsc_in, int* __restrict__ bsc_out)
{
    __shared__ int s[256];
    const int t = threadIdx.x;
    for (int pass = 0; pass < 2; ++pass) {
        const int* c = pass ? bcnt_out : bcnt_in;
        int* o = pass ? bsc_out : bsc_in;
        const int v = (t < NB) ? c[t] : 0;
        s[t] = v;
        __syncthreads();
        #pragma unroll
        for (int off = 1; off < 256; off <<= 1) {
            const int tv = (t >= off) ? s[t - off] : 0;
            __syncthreads();
            s[t] += tv;
            __syncthreads();
        }
        if (t < NB) o[t] = s[t] - v;
        if (t == NB - 1) o[NB] = s[t];
        __syncthreads();
    }
}

// per-bucket: histogram -> dinv + rp, then fill col array (merged, no weights)
__global__ __launch_bounds__(512)
void bdegfill_k(const int* __restrict__ ebuf_in, const int* __restrict__ ebuf_out,
                const int* __restrict__ bcnt_in, const int* __restrict__ bcnt_out,
                const int* __restrict__ bsc_in, const int* __restrict__ bsc_out,
                float* __restrict__ dinv_in, float* __restrict__ dinv_out,
                int* __restrict__ rp_in, int* __restrict__ rp_out,
                int* __restrict__ col_in, int* __restrict__ col_out, int N, int E)
{
    __shared__ int cnt[512];
    __shared__ int cur[512];
    const int t = threadIdx.x;
    const int dir = (blockIdx.x >= NB) ? 1 : 0;
    const int b = blockIdx.x - dir * NB;
    const int* ebuf = dir ? ebuf_out : ebuf_in;
    const int ne = (dir ? bcnt_out : bcnt_in)[b];
    const int base = (dir ? bsc_out : bsc_in)[b];
    const int e0 = b * CAP;

    cnt[t] = 0;
    __syncthreads();
    for (int j = t; j < ne; j += 512) atomicAdd(&cnt[ebuf[e0 + j] & 511], 1);
    __syncthreads();

    const int node = b * 512 + t;
    const int deg = cnt[t];
    float* dinv = dir ? dinv_out : dinv_in;
    if (node < N) dinv[node] = (deg > 0) ? rsqrtf((float)deg) : 0.f;

    // inclusive scan of cnt
    #pragma unroll
    for (int off = 1; off < 512; off <<= 1) {
        const int tv = (t >= off) ? cnt[t - off] : 0;
        __syncthreads();
        cnt[t] += tv;
        __syncthreads();
    }
    int* rp = dir ? rp_out : rp_in;
    if (node < N) rp[node] = base + cnt[t] - deg;
    if (b == 0 && t == 0) rp[N] = E;
    cur[t] = cnt[t] - deg;     // local start offset
    __syncthreads();

    int* col = dir ? col_out : col_in;
    for (int j = t; j < ne; j += 512) {
        const int p = ebuf[e0 + j];
        const int slot = atomicAdd(&cur[p & 511], 1);
        col[base + slot] = p >> 9;
    }
}

// ================= fused 2-direction gather =================
// y[n] = ybase_bf[n] + dinv_in[n]*sum(h_in[col]) + dinv_out[n]*sum(h_out[col])
// RELU_BF16: yout bf16 = relu(y);   else: yout fp32 = y
template<int F, bool RELU_BF16>
__global__ __launch_bounds__(256)
void gather2_k(const unsigned short* __restrict__ h_in,
               const unsigned short* __restrict__ h_out,
               const int* __restrict__ rp_in,  const int* __restrict__ col_in,
               const int* __restrict__ rp_out, const int* __restrict__ col_out,
               const float* __restrict__ dinv_in, const float* __restrict__ dinv_out,
               const unsigned short* __restrict__ ybase, void* __restrict__ yout, int N)
{
    constexpr int TPN = F / 8;
    const int tid = blockIdx.x * 256 + threadIdx.x;
    const int n = tid / TPN;
    if (n >= N) return;
    const int c8 = (tid % TPN) * 8;

    float acc_i[8] = {}, acc_o[8] = {};

    #pragma unroll 1
    for (int pass = 0; pass < 2; ++pass) {
        const int* rp  = pass ? rp_out  : rp_in;
        const int* col = pass ? col_out : col_in;
        const unsigned short* h = pass ? h_out : h_in;
        float* acc = pass ? acc_o : acc_i;
        const int beg = rp[n], end = rp[n + 1];
        int j = beg;
        for (; j + 2 <= end; j += 2) {
            const int g0 = col[j], g1 = col[j + 1];
            const int4 v0 = *(const int4*)(h + (size_t)g0 * F + c8);
            const int4 v1 = *(const int4*)(h + (size_t)g1 * F + c8);
            const unsigned short* p0 = (const unsigned short*)&v0;
            const unsigned short* p1 = (const unsigned short*)&v1;
            #pragma unroll
            for (int u = 0; u < 8; ++u) acc[u] += bf2f(p0[u]);
            #pragma unroll
            for (int u = 0; u < 8; ++u) acc[u] += bf2f(p1[u]);
        }
        if (j < end) {
            const int g0 = col[j];
            const int4 v0 = *(const int4*)(h + (size_t)g0 * F + c8);
            const unsigned short* p0 = (const unsigned short*)&v0;
            #pragma unroll
            for (int u = 0; u < 8; ++u) acc[u] += bf2f(p0[u]);
        }
    }

    const float di = dinv_in[n], dq = dinv_out[n];
    const int4 yb4 = *(const int4*)(ybase + (size_t)n * F + c8);
    const unsigned short* yb = (const unsigned short*)&yb4;

    float v[8];
    #pragma unroll
    for (int u = 0; u < 8; ++u)
        v[u] = bf2f(yb[u]) + di * acc_i[u] + dq * acc_o[u];

    if (RELU_BF16) {
        unsigned short o[8];
        #pragma unroll
        for (int u = 0; u < 8; ++u) o[u] = f2bf(fmaxf(v[u], 0.f));
        *(int4*)((unsigned short*)yout + (size_t)n * F + c8) = *(int4*)o;
    } else {
        float* yp = (float*)yout + (size_t)n * F + c8;
        *(float4*)yp       = make_float4(v[0], v[1], v[2], v[3]);
        *(float4*)(yp + 4) = make_float4(v[4], v[5], v[6], v[7]);
    }
}

// ================= launch =================
extern "C" void kernel_launch(void* const* d_in, const int* in_sizes, int n_in,
                              void* d_out, int out_size, void* d_ws, size_t ws_size,
                              hipStream_t stream)
{
    const int N = 100000, E = 800000, C = 64, H = 128;
    const int Npad = ((N + 63) / 64) * 64;          // 100032

    const float* x       = (const float*)d_in[0];
    const int*   ei      = (const int*)d_in[1];
    const int*   src     = ei;
    const int*   dst     = ei + E;
    const float* W1_in   = (const float*)d_in[2];
    const float* W1_out  = (const float*)d_in[3];
    const float* W1_root = (const float*)d_in[4];
    const float* b1      = (const float*)d_in[5];
    const float* W2_in   = (const float*)d_in[6];
    const float* W2_out  = (const float*)d_in[7];
    const float* W2_root = (const float*)d_in[8];
    const float* b2      = (const float*)d_in[9];
    float* out = (float*)d_out;

    // ---- workspace layout ----
    char* p = (char*)d_ws;
    int*   bcnt_in  = (int*)p;            p += (size_t)(2 * NB + 8) * 4;
    int*   bcnt_out = bcnt_in + NB;
    int*   bsc_in   = (int*)p;            p += (size_t)(2 * (NB + 1) + 8) * 4;
    int*   bsc_out  = bsc_in + NB + 1;
    float* dinv_in  = (float*)p;          p += (size_t)N * 4;
    float* dinv_out = (float*)p;          p += (size_t)N * 4;
    int*   rp_in    = (int*)p;            p += (size_t)(N + 8) * 4;
    int*   rp_out   = (int*)p;            p += (size_t)(N + 8) * 4;
    int*   col_in   = (int*)p;            p += (size_t)E * 4;
    int*   col_out  = (int*)p;            p += (size_t)E * 4;
    int*   ebuf_in  = (int*)p;            p += (size_t)NB * CAP * 4;
    int*   ebuf_out = (int*)p;            p += (size_t)NB * CAP * 4;
    unsigned short* wt1 = (unsigned short*)p;       p += (size_t)384 * 128 * 2;
    unsigned short* wt2 = (unsigned short*)p;       p += (size_t)192 * 128 * 2;
    unsigned short* xb  = (unsigned short*)p;       p += (size_t)Npad * 128 * 2;  // layer-2 input
    unsigned short* y1b = (unsigned short*)p;       p += (size_t)Npad * 128 * 2;  // root outputs
    unsigned short* h_in = (unsigned short*)p;      p += (size_t)Npad * 128 * 2;
    unsigned short* h_out= (unsigned short*)p;      p += (size_t)Npad * 128 * 2;

    const dim3 blk(256);

    // ---- bucketed CSR build ----
    zero_i_k<<<(2 * NB + 255) / 256, blk, 0, stream>>>(bcnt_in, 2 * NB);
    bscatter_k<<<SBLK, blk, 0, stream>>>(src, dst, bcnt_in, bcnt_out,
                                         ebuf_in, ebuf_out, E);
    bscan_k<<<1, blk, 0, stream>>>(bcnt_in, bcnt_out, bsc_in, bsc_out);
    bdegfill_k<<<2 * NB, 512, 0, stream>>>(ebuf_in, ebuf_out, bcnt_in, bcnt_out,
                                           bsc_in, bsc_out, dinv_in, dinv_out,
                                           rp_in, rp_out, col_in, col_out, N, E);

    // ---- weights ----
    wtrans_all_k<<<288, blk, 0, stream>>>(W1_root, W1_in, W1_out, W2_root, W2_in, W2_out,
                                          wt1, wt2);

    const int gemm_blocks = Npad / 64;   // 1563
    const int ga1 = (N * (H / 8) + 255) / 256;
    const int ga2 = (N * (C / 8) + 255) / 256;

    // ---- layer 1: one GEMM (fp32 A, converts in-stage), then fused gather ----
    gemm3_k<128, true><<<gemm_blocks, blk, 0, stream>>>(
        x, wt1, b1, dinv_in, dinv_out, y1b, h_in, h_out, N);
    gather2_k<128, true><<<ga1, blk, 0, stream>>>(
        h_in, h_out, rp_in, col_in, rp_out, col_out,
        dinv_in, dinv_out, y1b, xb, N);

    // ---- layer 2 ----
    gemm3_k<64, false><<<gemm_blocks, blk, 0, stream>>>(
        xb, wt2, b2, dinv_in, dinv_out, y1b, h_in, h_out, N);
    gather2_k<64, false><<<ga2, blk, 0, stream>>>(
        h_in, h_out, rp_in, col_in, rp_out, col_out,
        dinv_in, dinv_out, y1b, out, N);
}

// Round 6
// 269.089 us; speedup vs baseline: 16.2572x; 1.0151x over previous
//
#include <hip/hip_runtime.h>

typedef __attribute__((ext_vector_type(8))) short bf16x8;
typedef __attribute__((ext_vector_type(4))) float f32x4;

#define NB 196       // node buckets of 512
#define CAP 8192     // per-bucket edge capacity (avg 4096, sigma ~64)
#define SBLK 256     // bscatter blocks
#define ECH 3125     // edges per bscatter block

__device__ __forceinline__ unsigned short f2bf(float f) {
    unsigned int u = __float_as_uint(f);
    u = (u + 0x7FFFu + ((u >> 16) & 1u)) >> 16;   // RTNE
    return (unsigned short)u;
}
__device__ __forceinline__ float bf2f(unsigned short v) {
    return __uint_as_float(((unsigned int)v) << 16);
}

// ================= 3-weight MFMA GEMM =================
// A[nrows][128] (fp32 source or bf16 buffer) @ BTcat[w][BNW][128]^T, w=0,1,2
// w=0: +bias -> Y0 bf16;  w=1: *0.5*dinv_in[row] -> Y1;  w=2: *0.5*dinv_out[row] -> Y2
template<int BNW, bool A_FP32>
__global__ __launch_bounds__(256)
void gemm3_k(const void* __restrict__ Av,
             const unsigned short* __restrict__ BTcat,
             const float* __restrict__ bias,
             const float* __restrict__ dinv_in, const float* __restrict__ dinv_out,
             unsigned short* __restrict__ Y0, unsigned short* __restrict__ Y1,
             unsigned short* __restrict__ Y2, int nrows)
{
    constexpr int CF = BNW / 32;            // col frags per wave
    __shared__ unsigned short As[64 * 128];
    __shared__ unsigned short Bs[BNW * 128];

    const int t  = threadIdx.x;
    const int w  = t >> 6, l = t & 63;
    const int g  = l >> 4, li = l & 15;
    const int wr = w >> 1, wc = w & 1;
    const int row0 = blockIdx.x * 64;

    // ---- stage A tile (swizzle: ck ^= row&7) ----
    if (A_FP32) {
        const float* Ag = (const float*)Av;
        #pragma unroll
        for (int i = 0; i < 4; ++i) {
            const int q   = t + 256 * i;
            const int row = q >> 4;
            const int ck  = q & 15;
            unsigned short o[8];
            if (row0 + row < nrows) {
                const float* src = Ag + (size_t)(row0 + row) * 128 + ck * 8;
                const float4 a = *(const float4*)src;
                const float4 b = *(const float4*)(src + 4);
                o[0]=f2bf(a.x); o[1]=f2bf(a.y); o[2]=f2bf(a.z); o[3]=f2bf(a.w);
                o[4]=f2bf(b.x); o[5]=f2bf(b.y); o[6]=f2bf(b.z); o[7]=f2bf(b.w);
            } else {
                #pragma unroll
                for (int u = 0; u < 8; ++u) o[u] = 0;
            }
            *(int4*)&As[row * 128 + ((ck ^ (row & 7)) << 3)] = *(int4*)o;
        }
    } else {
        const int4* Ag = (const int4*)((const unsigned short*)Av + (size_t)row0 * 128);
        #pragma unroll
        for (int i = 0; i < 4; ++i) {
            const int q   = t + 256 * i;
            const int row = q >> 4;
            const int ck  = q & 15;
            const int4 v  = Ag[q];
            *(int4*)&As[row * 128 + ((ck ^ (row & 7)) << 3)] = v;
        }
    }

    #pragma unroll 1
    for (int wgt = 0; wgt < 3; ++wgt) {
        __syncthreads();   // As ready / previous compute done
        // ---- stage Bs for this weight ----
        {
            const int4* Bg = (const int4*)(BTcat + (size_t)wgt * BNW * 128);
            #pragma unroll
            for (int i = 0; i < BNW / 16; ++i) {
                const int q   = t + 256 * i;
                const int row = q >> 4;
                const int ck  = q & 15;
                const int4 v  = Bg[q];
                *(int4*)&Bs[row * 128 + ((ck ^ (row & 7)) << 3)] = v;
            }
        }
        __syncthreads();

        f32x4 acc[2][CF];
        #pragma unroll
        for (int rf = 0; rf < 2; ++rf)
            #pragma unroll
            for (int cf = 0; cf < CF; ++cf)
                acc[rf][cf] = (f32x4){0.f, 0.f, 0.f, 0.f};

        #pragma unroll
        for (int kk = 0; kk < 4; ++kk) {
            bf16x8 av[2], bv[CF];
            #pragma unroll
            for (int rf = 0; rf < 2; ++rf) {
                const int ar = wr * 32 + rf * 16 + li;
                const int ck = (kk * 4 + g) ^ (ar & 7);
                av[rf] = *(const bf16x8*)&As[ar * 128 + (ck << 3)];
            }
            #pragma unroll
            for (int cf = 0; cf < CF; ++cf) {
                const int bc = wc * (BNW / 2) + cf * 16 + li;
                const int ck = (kk * 4 + g) ^ (bc & 7);
                bv[cf] = *(const bf16x8*)&Bs[bc * 128 + (ck << 3)];
            }
            #pragma unroll
            for (int rf = 0; rf < 2; ++rf)
                #pragma unroll
                for (int cf = 0; cf < CF; ++cf)
                    acc[rf][cf] = __builtin_amdgcn_mfma_f32_16x16x32_bf16(
                        av[rf], bv[cf], acc[rf][cf], 0, 0, 0);
        }

        unsigned short* Y = (wgt == 0) ? Y0 : (wgt == 1) ? Y1 : Y2;
        const float* dv = (wgt == 1) ? dinv_in : dinv_out;
        #pragma unroll
        for (int rf = 0; rf < 2; ++rf) {
            #pragma unroll
            for (int i = 0; i < 4; ++i) {
                const int r = row0 + wr * 32 + rf * 16 + 4 * g + i;
                if (r < nrows) {
                    const float s = (wgt == 0) ? 1.f : 0.5f * dv[r];
                    #pragma unroll
                    for (int cf = 0; cf < CF; ++cf) {
                        const int c = wc * (BNW / 2) + cf * 16 + li;
                        float v = acc[rf][cf][i];
                        v = (wgt == 0) ? (v + bias[c]) : (v * s);
                        Y[(size_t)r * BNW + c] = f2bf(v);
                    }
                }
            }
        }
    }
}

// ================= weight transpose: cat layout [root|in|out] =================
__global__ __launch_bounds__(256)
void wtrans_all_k(const float* __restrict__ W1r, const float* __restrict__ W1i,
                  const float* __restrict__ W1o, const float* __restrict__ W2r,
                  const float* __restrict__ W2i, const float* __restrict__ W2o,
                  unsigned short* __restrict__ T1, unsigned short* __restrict__ T2)
{
    const int tid = blockIdx.x * 256 + threadIdx.x;   // 0..73727
    if (tid >= 3 * 16384 + 3 * 8192) return;
    const float* W; unsigned short* T; int M, r, base;
    if (tid < 49152) {
        const int w = tid / 16384; r = tid % 16384; M = 128;
        W = (w == 0) ? W1r : (w == 1) ? W1i : W1o;
        T = T1; base = w * 128;
    } else {
        const int u = tid - 49152;
        const int w = u / 8192; r = u % 8192; M = 64;
        W = (w == 0) ? W2r : (w == 1) ? W2i : W2o;
        T = T2; base = w * 64;
    }
    const int m = r & (M - 1);
    const int k = r / M;
    T[(size_t)(base + m) * 128 + k] = f2bf(W[(size_t)k * M + m]);
}

// ================= bucketed CSR build =================
__global__ __launch_bounds__(256)
void zero_i_k(int* __restrict__ p, int n)
{
    const int i = blockIdx.x * 256 + threadIdx.x;
    if (i < n) p[i] = 0;
}

// scatter edges into per-bucket streams (two-pass, LDS counters)
__global__ __launch_bounds__(256)
void bscatter_k(const int* __restrict__ src, const int* __restrict__ dst,
                int* __restrict__ bcnt_in, int* __restrict__ bcnt_out,
                int* __restrict__ ebuf_in, int* __restrict__ ebuf_out, int E)
{
    __shared__ int lcnt_d[NB], lcnt_s[NB], lbase_d[NB], lbase_s[NB];
    const int t = threadIdx.x;
    const int c0 = blockIdx.x * ECH;
    const int c1 = min(E, c0 + ECH);
    for (int i = t; i < NB; i += 256) { lcnt_d[i] = 0; lcnt_s[i] = 0; }
    __syncthreads();
    for (int e = c0 + t; e < c1; e += 256) {
        atomicAdd(&lcnt_d[dst[e] >> 9], 1);
        atomicAdd(&lcnt_s[src[e] >> 9], 1);
    }
    __syncthreads();
    for (int b = t; b < NB; b += 256) {
        lbase_d[b] = atomicAdd(&bcnt_in[b],  lcnt_d[b]);
        lbase_s[b] = atomicAdd(&bcnt_out[b], lcnt_s[b]);
        lcnt_d[b] = 0; lcnt_s[b] = 0;
    }
    __syncthreads();
    for (int e = c0 + t; e < c1; e += 256) {
        const int s = src[e], d = dst[e];
        const int bd = d >> 9, bs = s >> 9;
        const int rd = atomicAdd(&lcnt_d[bd], 1);
        ebuf_in [bd * CAP + lbase_d[bd] + rd] = (s << 9) | (d & 511);
        const int rs = atomicAdd(&lcnt_s[bs], 1);
        ebuf_out[bs * CAP + lbase_s[bs] + rs] = (d << 9) | (s & 511);
    }
}

// exclusive scan over bucket counts (both directions), single block
__global__ __launch_bounds__(256)
void bscan_k(const int* __restrict__ bcnt_in, const int* __restrict__ bcnt_out,
             int* __restrict__ bsc_in, int* __restrict__ bsc_out)
{
    __shared__ int s[256];
    const int t = threadIdx.x;
    for (int pass = 0; pass < 2; ++pass) {
        const int* c = pass ? bcnt_out : bcnt_in;
        int* o = pass ? bsc_out : bsc_in;
        const int v = (t < NB) ? c[t] : 0;
        s[t] = v;
        __syncthreads();
        #pragma unroll
        for (int off = 1; off < 256; off <<= 1) {
            const int tv = (t >= off) ? s[t - off] : 0;
            __syncthreads();
            s[t] += tv;
            __syncthreads();
        }
        if (t < NB) o[t] = s[t] - v;
        if (t == NB - 1) o[NB] = s[t];
        __syncthreads();
    }
}

// per-bucket: histogram -> dinv + rp, then fill col array (merged, no weights)
__global__ __launch_bounds__(512)
void bdegfill_k(const int* __restrict__ ebuf_in, const int* __restrict__ ebuf_out,
                const int* __restrict__ bcnt_in, const int* __restrict__ bcnt_out,
                const int* __restrict__ bsc_in, const int* __restrict__ bsc_out,
                float* __restrict__ dinv_in, float* __restrict__ dinv_out,
                int* __restrict__ rp_in, int* __restrict__ rp_out,
                int* __restrict__ col_in, int* __restrict__ col_out, int N, int E)
{
    __shared__ int cnt[512];
    __shared__ int cur[512];
    const int t = threadIdx.x;
    const int dir = (blockIdx.x >= NB) ? 1 : 0;
    const int b = blockIdx.x - dir * NB;
    const int* ebuf = dir ? ebuf_out : ebuf_in;
    const int ne = (dir ? bcnt_out : bcnt_in)[b];
    const int base = (dir ? bsc_out : bsc_in)[b];
    const int e0 = b * CAP;

    cnt[t] = 0;
    __syncthreads();
    for (int j = t; j < ne; j += 512) atomicAdd(&cnt[ebuf[e0 + j] & 511], 1);
    __syncthreads();

    const int node = b * 512 + t;
    const int deg = cnt[t];
    float* dinv = dir ? dinv_out : dinv_in;
    if (node < N) dinv[node] = (deg > 0) ? rsqrtf((float)deg) : 0.f;

    // inclusive scan of cnt
    #pragma unroll
    for (int off = 1; off < 512; off <<= 1) {
        const int tv = (t >= off) ? cnt[t - off] : 0;
        __syncthreads();
        cnt[t] += tv;
        __syncthreads();
    }
    int* rp = dir ? rp_out : rp_in;
    if (node < N) rp[node] = base + cnt[t] - deg;
    if (b == 0 && t == 0) rp[N] = E;
    cur[t] = cnt[t] - deg;     // local start offset
    __syncthreads();

    int* col = dir ? col_out : col_in;
    for (int j = t; j < ne; j += 512) {
        const int p = ebuf[e0 + j];
        const int slot = atomicAdd(&cur[p & 511], 1);
        col[base + slot] = p >> 9;
    }
}

// ================= fused 2-direction gather (software-pipelined, unroll-4) =================
// y[n] = ybase_bf[n] + dinv_in[n]*sum(h_in[col]) + dinv_out[n]*sum(h_out[col])
// RELU_BF16: yout bf16 = relu(y);   else: yout fp32 = y
__device__ __forceinline__ void accum8(float* acc, const int4 v) {
    const unsigned short* pp = (const unsigned short*)&v;
    #pragma unroll
    for (int u = 0; u < 8; ++u) acc[u] += bf2f(pp[u]);
}

template<int F, bool RELU_BF16>
__global__ __launch_bounds__(256)
void gather2_k(const unsigned short* __restrict__ h_in,
               const unsigned short* __restrict__ h_out,
               const int* __restrict__ rp_in,  const int* __restrict__ col_in,
               const int* __restrict__ rp_out, const int* __restrict__ col_out,
               const float* __restrict__ dinv_in, const float* __restrict__ dinv_out,
               const unsigned short* __restrict__ ybase, void* __restrict__ yout, int N)
{
    constexpr int TPN = F / 8;
    const int tid = blockIdx.x * 256 + threadIdx.x;
    const int n = tid / TPN;
    if (n >= N) return;
    const int c8 = (tid % TPN) * 8;

    // hoist independent loads: rp bounds, dinv, ybase all issue up front
    const int bi = rp_in[n],  ei = rp_in[n + 1];
    const int bo = rp_out[n], eo = rp_out[n + 1];
    const float di = dinv_in[n], dq = dinv_out[n];
    const int4 yb4 = *(const int4*)(ybase + (size_t)n * F + c8);

    const unsigned short* hi = h_in + c8;
    const unsigned short* ho = h_out + c8;

    float acc_i[8] = {}, acc_o[8] = {};

    #pragma unroll 1
    for (int pass = 0; pass < 2; ++pass) {
        const int beg = pass ? bo : bi;
        const int end = pass ? eo : ei;
        const int* col = pass ? col_out : col_in;
        const unsigned short* h = pass ? ho : hi;
        float* acc = pass ? acc_o : acc_i;

        int j = beg;
        if (j + 4 <= end) {
            // software pipeline: cols for iter k+1 load while rows of iter k are in flight
            int c0 = col[j], c1 = col[j + 1], c2 = col[j + 2], c3 = col[j + 3];
            for (; j + 8 <= end; j += 4) {
                const int4 v0 = *(const int4*)(h + (size_t)c0 * F);
                const int4 v1 = *(const int4*)(h + (size_t)c1 * F);
                const int4 v2 = *(const int4*)(h + (size_t)c2 * F);
                const int4 v3 = *(const int4*)(h + (size_t)c3 * F);
                c0 = col[j + 4]; c1 = col[j + 5]; c2 = col[j + 6]; c3 = col[j + 7];
                accum8(acc, v0); accum8(acc, v1); accum8(acc, v2); accum8(acc, v3);
            }
            // drain preloaded quad
            const int4 v0 = *(const int4*)(h + (size_t)c0 * F);
            const int4 v1 = *(const int4*)(h + (size_t)c1 * F);
            const int4 v2 = *(const int4*)(h + (size_t)c2 * F);
            const int4 v3 = *(const int4*)(h + (size_t)c3 * F);
            accum8(acc, v0); accum8(acc, v1); accum8(acc, v2); accum8(acc, v3);
            j += 4;
        }
        // tail 0..3 edges, keep loads independent
        if (j < end) {
            const int rem = end - j;
            const int c0 = col[j];
            const int c1 = (rem > 1) ? col[j + 1] : c0;
            const int c2 = (rem > 2) ? col[j + 2] : c0;
            const int4 v0 = *(const int4*)(h + (size_t)c0 * F);
            if (rem > 1) {
                const int4 v1 = *(const int4*)(h + (size_t)c1 * F);
                accum8(acc, v1);
            }
            if (rem > 2) {
                const int4 v2 = *(const int4*)(h + (size_t)c2 * F);
                accum8(acc, v2);
            }
            accum8(acc, v0);
        }
    }

    const unsigned short* yb = (const unsigned short*)&yb4;
    float v[8];
    #pragma unroll
    for (int u = 0; u < 8; ++u)
        v[u] = bf2f(yb[u]) + di * acc_i[u] + dq * acc_o[u];

    if (RELU_BF16) {
        unsigned short o[8];
        #pragma unroll
        for (int u = 0; u < 8; ++u) o[u] = f2bf(fmaxf(v[u], 0.f));
        *(int4*)((unsigned short*)yout + (size_t)n * F + c8) = *(int4*)o;
    } else {
        float* yp = (float*)yout + (size_t)n * F + c8;
        *(float4*)yp       = make_float4(v[0], v[1], v[2], v[3]);
        *(float4*)(yp + 4) = make_float4(v[4], v[5], v[6], v[7]);
    }
}

// ================= launch =================
extern "C" void kernel_launch(void* const* d_in, const int* in_sizes, int n_in,
                              void* d_out, int out_size, void* d_ws, size_t ws_size,
                              hipStream_t stream)
{
    const int N = 100000, E = 800000, C = 64, H = 128;
    const int Npad = ((N + 63) / 64) * 64;          // 100032

    const float* x       = (const float*)d_in[0];
    const int*   ei      = (const int*)d_in[1];
    const int*   src     = ei;
    const int*   dst     = ei + E;
    const float* W1_in   = (const float*)d_in[2];
    const float* W1_out  = (const float*)d_in[3];
    const float* W1_root = (const float*)d_in[4];
    const float* b1      = (const float*)d_in[5];
    const float* W2_in   = (const float*)d_in[6];
    const float* W2_out  = (const float*)d_in[7];
    const float* W2_root = (const float*)d_in[8];
    const float* b2      = (const float*)d_in[9];
    float* out = (float*)d_out;

    // ---- workspace layout ----
    char* p = (char*)d_ws;
    int*   bcnt_in  = (int*)p;            p += (size_t)(2 * NB + 8) * 4;
    int*   bcnt_out = bcnt_in + NB;
    int*   bsc_in   = (int*)p;            p += (size_t)(2 * (NB + 1) + 8) * 4;
    int*   bsc_out  = bsc_in + NB + 1;
    float* dinv_in  = (float*)p;          p += (size_t)N * 4;
    float* dinv_out = (float*)p;          p += (size_t)N * 4;
    int*   rp_in    = (int*)p;            p += (size_t)(N + 8) * 4;
    int*   rp_out   = (int*)p;            p += (size_t)(N + 8) * 4;
    int*   col_in   = (int*)p;            p += (size_t)E * 4;
    int*   col_out  = (int*)p;            p += (size_t)E * 4;
    int*   ebuf_in  = (int*)p;            p += (size_t)NB * CAP * 4;
    int*   ebuf_out = (int*)p;            p += (size_t)NB * CAP * 4;
    unsigned short* wt1 = (unsigned short*)p;       p += (size_t)384 * 128 * 2;
    unsigned short* wt2 = (unsigned short*)p;       p += (size_t)192 * 128 * 2;
    unsigned short* xb  = (unsigned short*)p;       p += (size_t)Npad * 128 * 2;  // layer-2 input
    unsigned short* y1b = (unsigned short*)p;       p += (size_t)Npad * 128 * 2;  // root outputs
    unsigned short* h_in = (unsigned short*)p;      p += (size_t)Npad * 128 * 2;
    unsigned short* h_out= (unsigned short*)p;      p += (size_t)Npad * 128 * 2;

    const dim3 blk(256);

    // ---- bucketed CSR build ----
    zero_i_k<<<(2 * NB + 255) / 256, blk, 0, stream>>>(bcnt_in, 2 * NB);
    bscatter_k<<<SBLK, blk, 0, stream>>>(src, dst, bcnt_in, bcnt_out,
                                         ebuf_in, ebuf_out, E);
    bscan_k<<<1, blk, 0, stream>>>(bcnt_in, bcnt_out, bsc_in, bsc_out);
    bdegfill_k<<<2 * NB, 512, 0, stream>>>(ebuf_in, ebuf_out, bcnt_in, bcnt_out,
                                           bsc_in, bsc_out, dinv_in, dinv_out,
                                           rp_in, rp_out, col_in, col_out, N, E);

    // ---- weights ----
    wtrans_all_k<<<288, blk, 0, stream>>>(W1_root, W1_in, W1_out, W2_root, W2_in, W2_out,
                                          wt1, wt2);

    const int gemm_blocks = Npad / 64;   // 1563
    const int ga1 = (N * (H / 8) + 255) / 256;
    const int ga2 = (N * (C / 8) + 255) / 256;

    // ---- layer 1: one GEMM (fp32 A, converts in-stage), then fused gather ----
    gemm3_k<128, true><<<gemm_blocks, blk, 0, stream>>>(
        x, wt1, b1, dinv_in, dinv_out, y1b, h_in, h_out, N);
    gather2_k<128, true><<<ga1, blk, 0, stream>>>(
        h_in, h_out, rp_in, col_in, rp_out, col_out,
        dinv_in, dinv_out, y1b, xb, N);

    // ---- layer 2 ----
    gemm3_k<64, false><<<gemm_blocks, blk, 0, stream>>>(
        xb, wt2, b2, dinv_in, dinv_out, y1b, h_in, h_out, N);
    gather2_k<64, false><<<ga2, blk, 0, stream>>>(
        h_in, h_out, rp_in, col_in, rp_out, col_out,
        dinv_in, dinv_out, y1b, out, N);
}